// Round 11
// baseline (138.135 us; speedup 1.0000x reference)
//
#include <hip/hip_runtime.h>
#include <math.h>

namespace {

typedef __bf16 bf16_t;
typedef bf16_t bf16x8 __attribute__((ext_vector_type(8)));
typedef bf16_t bf16x4 __attribute__((ext_vector_type(4)));
typedef float f32x4 __attribute__((ext_vector_type(4)));

constexpr int B = 8, L = 101, DIM = 1024, H = 8, DH = 128, MF = 621, MFP = 640;
constexpr int BL = B * L;    // 808
constexpr int BLP = 832;     // padded rows for GEMM A
constexpr int BH = B * H;    // 64
constexpr int RR = BL * H;   // 6464

constexpr float DN    = 0.29730177875068026f;   // 128^-0.25
constexpr float DN2   = 0.08838834764831845f;   // 128^-0.5
constexpr float RATIO = 0.04012861672f;         // 621^-0.5
constexpr float EPS   = 1e-4f;

// split_all segment sizes (bf16x4 / float4 units)
constexpr int NX = BL * DIM / 4;    // 206848
constexpr int NP = MFP * 32;        // 20480  (proj -> ph only)
constexpr int NR = 64 * DH / 4;     // 2048   (rpe, padded to 64 rows, split)
constexpr int NW = DIM * DIM / 4;   // 262144
constexpr int NZ = 4 * (BLP - BL) * DIM / 4;  // 24576 pad-zero units (xh,xl,qh,ql)
constexpr int NV = BH * DH / 4;     // 2048 (vsum zero)
constexpr int NTOT = NX + NP + NR + 3 * NW + NZ + NV;

__device__ __forceinline__ f32x4 mfma16(bf16x8 a, bf16x8 b, f32x4 c) {
  return __builtin_amdgcn_mfma_f32_16x16x32_bf16(a, b, c, 0, 0, 0);
}

__device__ __forceinline__ void split2(float f, bf16_t& h, bf16_t& l) {
  h = (bf16_t)f;
  l = (bf16_t)(f - (float)h);
}

__device__ __forceinline__ void gload_lds16(const bf16_t* g, bf16_t* l) {
  __builtin_amdgcn_global_load_lds(
      (const __attribute__((address_space(1))) void*)g,
      (__attribute__((address_space(3))) void*)l, 16, 0, 0);
}

// ---------- one-shot convert/split of everything (+ vsum zero) ----------
__global__ __launch_bounds__(256) void split_all(const float* __restrict__ x,
                                                 const float* __restrict__ proj,
                                                 const float* __restrict__ rpe,
                                                 const float* __restrict__ Wq,
                                                 const float* __restrict__ Wv,
                                                 const float* __restrict__ Wo,
                                                 bf16_t* __restrict__ xh, bf16_t* __restrict__ xl,
                                                 bf16_t* __restrict__ ph,
                                                 bf16_t* __restrict__ rh, bf16_t* __restrict__ rl,
                                                 bf16_t* __restrict__ Wh,
                                                 bf16_t* __restrict__ Woh,
                                                 bf16_t* __restrict__ qh, bf16_t* __restrict__ ql,
                                                 float* __restrict__ vsum) {
  const int u = blockIdx.x * 256 + threadIdx.x;
  if (u >= NTOT) return;
  auto emit2 = [](const float* s4, float sc, bf16_t* dh, bf16_t* dl, size_t off) {
    float4 f = *(const float4*)s4;
    bf16x4 hv, lv; bf16_t h, l;
    split2(f.x * sc, h, l); hv[0] = h; lv[0] = l;
    split2(f.y * sc, h, l); hv[1] = h; lv[1] = l;
    split2(f.z * sc, h, l); hv[2] = h; lv[2] = l;
    split2(f.w * sc, h, l); hv[3] = h; lv[3] = l;
    *(bf16x4*)(dh + off) = hv;
    *(bf16x4*)(dl + off) = lv;
  };
  auto emit1 = [](const float* s4, float sc, bf16_t* dh, size_t off) {
    float4 f = *(const float4*)s4;
    bf16x4 hv;
    hv[0] = (bf16_t)(f.x * sc); hv[1] = (bf16_t)(f.y * sc);
    hv[2] = (bf16_t)(f.z * sc); hv[3] = (bf16_t)(f.w * sc);
    *(bf16x4*)(dh + off) = hv;
  };
  int t = u;
  if (t < NX) { emit2(x + (size_t)t * 4, 1.f, xh, xl, (size_t)t * 4); return; }
  t -= NX;
  if (t < NP) {
    if ((t >> 5) < MF) emit1(proj + (size_t)t * 4, DN, ph, (size_t)t * 4);
    else { bf16x4 z = {}; *(bf16x4*)(ph + (size_t)t * 4) = z; }
    return;
  }
  t -= NP;
  if (t < NR) {
    if (t < 5 * DH / 4) emit2(rpe + (size_t)t * 4, 1.f, rh, rl, (size_t)t * 4);
    else { bf16x4 z = {}; *(bf16x4*)(rh + (size_t)t * 4) = z; *(bf16x4*)(rl + (size_t)t * 4) = z; }
    return;
  }
  t -= NR;
  if (t < NW) { emit1(Wq + (size_t)t * 4, 1.f, Wh, (size_t)t * 4); return; }
  t -= NW;
  if (t < NW) { emit1(Wv + (size_t)t * 4, 1.f, Wh, (size_t)(t + NW) * 4); return; }
  t -= NW;
  if (t < NW) { emit1(Wo + (size_t)t * 4, 1.f, Woh, (size_t)t * 4); return; }
  t -= NW;
  if (t < NZ) {  // zero pads rows 808..831 of xh,xl,qh,ql
    const int buf = t / 6144, o = t % 6144;
    bf16_t* dst = (buf == 0) ? xh : (buf == 1) ? xl : (buf == 2) ? qh : ql;
    bf16x4 z = {};
    *(bf16x4*)(dst + (size_t)BL * DIM + (size_t)o * 4) = z;
    return;
  }
  t -= NZ;
  ((float4*)vsum)[t] = make_float4(0.f, 0.f, 0.f, 0.f);
}

// ---------- BK=64 LDS-staged 2-term MFMA GEMM, block tile 64x64, 4 waves 32x32 ----------
// MODE 0: f32 out + bias0 (o-proj). MODE 1: qv — q bf16-split / v f32 + vsum atomics.
template<int MODE>
__global__ __launch_bounds__(256) void gemm64(const bf16_t* __restrict__ Ah,
                                              const bf16_t* __restrict__ Al,
                                              const bf16_t* __restrict__ Bh,
                                              const float* __restrict__ bias0,
                                              const float* __restrict__ bias1,
                                              float* __restrict__ Cf,
                                              bf16_t* __restrict__ Ch,
                                              bf16_t* __restrict__ Cl,
                                              float* __restrict__ vsum) {
  constexpr int K = 1024, BK = 64, NK = K / BK;   // 16 steps
  __shared__ bf16_t lds[2][3][64 * 64];           // [dbuf][Ah,Al,B]
  const int tid = threadIdx.x;
  const int w = tid >> 6, lane = tid & 63;
  const int wr = w >> 1, wc = w & 1;
  const int l15 = lane & 15, l4 = lane >> 4;
  const int rowBase = blockIdx.y * 64, colBase = blockIdx.x * 64;
  const int r8 = lane >> 3;                 // 0..7
  const int cs = (lane & 7) ^ r8;           // pre-swizzled source col16 group
  const bf16_t* src = (w == 0) ? Ah : (w == 1) ? Al : Bh;
  const int grow0 = (w < 2) ? rowBase : colBase + ((w == 3) ? 32 : 0);
  const bf16_t* srcL = src + (size_t)(grow0 + r8) * K + cs * 8;
  const int tt = (w < 2) ? w : 2;
  const int dst0 = (w == 3) ? 32 * 64 : 0;
  auto STAGE = [&](int bf, int k0) {
    if (w < 2) {
#pragma unroll
      for (int j = 0; j < 8; ++j)
        gload_lds16(srcL + (size_t)(8 * j) * K + k0, &lds[bf][tt][j * 512]);
    } else {
#pragma unroll
      for (int j = 0; j < 4; ++j)
        gload_lds16(srcL + (size_t)(8 * j) * K + k0, &lds[bf][2][dst0 + j * 512]);
    }
  };
  const int ra0 = wr * 32 + l15, ra1 = ra0 + 16;
  const int rb0 = wc * 32 + l15, rb1 = rb0 + 16;
  auto TADDR = [](int row, int kg) { return row * 64 + (((kg) ^ (row & 7)) << 3); };
  f32x4 acc[2][2] = {};
  STAGE(0, 0);
  __syncthreads();
  int bf = 0;
  for (int ks = 0; ks < NK; ++ks) {
    if (ks + 1 < NK) STAGE(bf ^ 1, (ks + 1) * BK);
#pragma unroll
    for (int subk = 0; subk < 2; ++subk) {
      const int kg = subk * 4 + l4;
      bf16x8 a0h = *(const bf16x8*)&lds[bf][0][TADDR(ra0, kg)];
      bf16x8 a0l = *(const bf16x8*)&lds[bf][1][TADDR(ra0, kg)];
      bf16x8 a1h = *(const bf16x8*)&lds[bf][0][TADDR(ra1, kg)];
      bf16x8 a1l = *(const bf16x8*)&lds[bf][1][TADDR(ra1, kg)];
      bf16x8 b0  = *(const bf16x8*)&lds[bf][2][TADDR(rb0, kg)];
      bf16x8 b1  = *(const bf16x8*)&lds[bf][2][TADDR(rb1, kg)];
      acc[0][0] = mfma16(a0h, b0, acc[0][0]);
      acc[0][0] = mfma16(a0l, b0, acc[0][0]);
      acc[0][1] = mfma16(a0h, b1, acc[0][1]);
      acc[0][1] = mfma16(a0l, b1, acc[0][1]);
      acc[1][0] = mfma16(a1h, b0, acc[1][0]);
      acc[1][0] = mfma16(a1l, b0, acc[1][0]);
      acc[1][1] = mfma16(a1h, b1, acc[1][1]);
      acc[1][1] = mfma16(a1l, b1, acc[1][1]);
    }
    __syncthreads();
    bf ^= 1;
  }
#pragma unroll
  for (int ni = 0; ni < 2; ++ni) {
    const int col = colBase + wc * 32 + ni * 16 + l15;
#pragma unroll
    for (int mi = 0; mi < 2; ++mi) {
      float vpart = 0.f;  // v-column partial sum (same b across flushes below)
      int curb = -1;
#pragma unroll
      for (int r2 = 0; r2 < 4; ++r2) {
        const int row = rowBase + wr * 32 + mi * 16 + l4 * 4 + r2;
        if (row < BL) {
          if (MODE == 0) {
            Cf[(size_t)row * 1024 + col] = acc[mi][ni][r2] + bias0[col];
          } else {
            if (col < 1024) {
              float val = acc[mi][ni][r2] + bias0[col];
              bf16_t h, lo; split2(val, h, lo);
              Ch[(size_t)row * 1024 + col] = h;
              Cl[(size_t)row * 1024 + col] = lo;
            } else {
              const int vcol = col - 1024;
              const float val = acc[mi][ni][r2] + bias1[vcol];
              Cf[(size_t)row * 1024 + vcol] = val;
              const int b = row / L;
              if (b != curb) {
                if (curb >= 0)
                  atomicAdd(&vsum[(size_t)(curb * 8) * DH + vcol], vpart);
                curb = b; vpart = 0.f;
              }
              vpart += val;
            }
          }
        }
      }
      if (MODE == 1 && curb >= 0)
        atomicAdd(&vsum[(size_t)(curb * 8) * DH + (col - 1024)], vpart);
    }
  }
}

// ---------- qf3: fused dd-GEMM + rf + maxes + exp + 5 reductions + gather-out ----------
// Block = 32 rows ((r0/8..r0/8+3) x 8 heads) x 640 cols; grid 202.
__global__ __launch_bounds__(256) void qf3_kernel(const bf16_t* __restrict__ qh,
                                                  const bf16_t* __restrict__ ql,
                                                  const bf16_t* __restrict__ rh,
                                                  const bf16_t* __restrict__ rl,
                                                  const bf16_t* __restrict__ ph,
                                                  const float* __restrict__ rpe,
                                                  const float* __restrict__ v,
                                                  const float* __restrict__ vsum,
                                                  bf16_t* __restrict__ attnh,
                                                  bf16_t* __restrict__ attnl) {
  const int tid = threadIdx.x;
  __shared__ bf16_t Ahl[2][64 * 128];   // [h,l][row*128]; rows 0..31 q, 32..63 rf(pad)
  __shared__ bf16_t Bch[2][64 * 128];   // [dbuf] chunk of ph
  __shared__ float rfs[5][MFP];
  __shared__ float diag[32];
  __shared__ float diag5v[8];
  __shared__ float mxs[4][32];
  __shared__ float mxAll[32];
  __shared__ float mxrf[4];
  __shared__ float sred[4][32][5];
  __shared__ float fdv[32][6];          // s0..s4, Dinv
  const int w = tid >> 6, lane = tid & 63;
  const int l15 = lane & 15, l4 = lane >> 4;
  const int r0 = blockIdx.x * 32;
  const int r4 = lane >> 4;        // 0..3
  const int cg = lane & 15;        // dest col16
  // ---- A stage (once) ----
  {
    const bf16_t* srcA = (w == 0) ? qh : (w == 1) ? ql : (w == 2) ? rh : rl;
    const int arow0 = (w < 2) ? r0 : 0;
    bf16_t* dstA = &Ahl[w & 1][(w >= 2 ? 32 : 0) * 128];
    const bf16_t* peA = srcA + (size_t)(arow0 + r4) * DH + ((cg ^ r4) << 3);
    const bf16_t* poA = srcA + (size_t)(arow0 + r4) * DH + ((cg ^ r4 ^ 4) << 3);
#pragma unroll
    for (int j = 0; j < 8; ++j)
      gload_lds16(((j & 1) ? poA : peA) + (size_t)(4 * j) * DH, dstA + j * 512);
  }
  // ---- B chunk stage ----
  const bf16_t* peB = ph + (size_t)(w * 16 + r4) * DH + ((cg ^ r4) << 3);
  const bf16_t* poB = ph + (size_t)(w * 16 + r4) * DH + ((cg ^ r4 ^ 4) << 3);
  auto STAGE_B = [&](int buf, int c) {
    const size_t coff = (size_t)c * 64 * DH;
#pragma unroll
    for (int j = 0; j < 4; ++j)
      gload_lds16(((j & 1) ? poB : peB) + coff + (size_t)(4 * j) * DH,
                  &Bch[buf][(w * 16 + j * 4) * 128]);
  };
  // ---- diag / diag5v ----
  {
    const int row = tid >> 3, ch = tid & 7;
    const size_t base = (size_t)(r0 + row) * DH + ch * 16;
    float s = 0.f;
#pragma unroll
    for (int t = 0; t < 2; ++t) {
      bf16x8 vh = *(const bf16x8*)(qh + base + t * 8);
      bf16x8 vl = *(const bf16x8*)(ql + base + t * 8);
#pragma unroll
      for (int e = 0; e < 8; ++e) {
        float f = (float)vh[e] + (float)vl[e];
        s += f * f;
      }
    }
    s += __shfl_xor(s, 1, 64); s += __shfl_xor(s, 2, 64); s += __shfl_xor(s, 4, 64);
    if (ch == 0) diag[row] = (0.5f * DN2) * s;
  }
  if (tid < 40) {
    const int row = tid >> 3, ch = tid & 7;
    float s = 0.f;
#pragma unroll
    for (int e = 0; e < 16; ++e) { float f = rpe[row * DH + ch * 16 + e]; s += f * f; }
    s += __shfl_xor(s, 1, 64); s += __shfl_xor(s, 2, 64); s += __shfl_xor(s, 4, 64);
    if (ch == 0) diag5v[row] = (0.5f * DN2) * s;
  }
  // ---- main loop: 10 chunks x 4 k-steps ----
  auto TADDR = [](int row, int kg) { return row * 128 + (((kg) ^ (row & 7)) << 3); };
  f32x4 acc[2][10] = {};
  f32x4 accr[10] = {};
  STAGE_B(0, 0);
  __syncthreads();
  int buf = 0;
#pragma unroll
  for (int c = 0; c < 10; ++c) {
    if (c + 1 < 10) STAGE_B(buf ^ 1, c + 1);
#pragma unroll
    for (int ks = 0; ks < 4; ++ks) {
      const int kg = ks * 4 + l4;
      bf16x8 a0h = *(const bf16x8*)&Ahl[0][TADDR(l15, kg)];
      bf16x8 a0l = *(const bf16x8*)&Ahl[1][TADDR(l15, kg)];
      bf16x8 a1h = *(const bf16x8*)&Ahl[0][TADDR(16 + l15, kg)];
      bf16x8 a1l = *(const bf16x8*)&Ahl[1][TADDR(16 + l15, kg)];
      bf16x8 arh = *(const bf16x8*)&Ahl[0][TADDR(32 + l15, kg)];
      bf16x8 arl = *(const bf16x8*)&Ahl[1][TADDR(32 + l15, kg)];
      bf16x8 bb  = *(const bf16x8*)&Bch[buf][TADDR(w * 16 + l15, kg)];
      acc[0][c] = mfma16(a0h, bb, acc[0][c]);
      acc[0][c] = mfma16(a0l, bb, acc[0][c]);
      acc[1][c] = mfma16(a1h, bb, acc[1][c]);
      acc[1][c] = mfma16(a1l, bb, acc[1][c]);
      accr[c]   = mfma16(arh, bb, accr[c]);
      accr[c]   = mfma16(arl, bb, accr[c]);
    }
    __syncthreads();
    buf ^= 1;
  }
  // ---- q per-row max ----
  float pm[2][4];
#pragma unroll
  for (int mi = 0; mi < 2; ++mi)
#pragma unroll
    for (int r2 = 0; r2 < 4; ++r2) {
      float m = -3.4e38f;
#pragma unroll
      for (int ni = 0; ni < 10; ++ni) {
        const int col = ni * 64 + w * 16 + l15;
        float vv = (col < MF) ? acc[mi][ni][r2] : -3.4e38f;
        m = fmaxf(m, vv);
      }
      pm[mi][r2] = m;
    }
#pragma unroll
  for (int mask = 1; mask <= 8; mask <<= 1)
#pragma unroll
    for (int mi = 0; mi < 2; ++mi)
#pragma unroll
      for (int r2 = 0; r2 < 4; ++r2)
        pm[mi][r2] = fmaxf(pm[mi][r2], __shfl_xor(pm[mi][r2], mask, 64));
  if (l15 == 0) {
#pragma unroll
    for (int mi = 0; mi < 2; ++mi)
#pragma unroll
      for (int r2 = 0; r2 < 4; ++r2)
        mxs[w][mi * 16 + l4 * 4 + r2] = pm[mi][r2];
  }
  // ---- rf global max ----
  {
    float m = -3.4e38f;
#pragma unroll
    for (int ni = 0; ni < 10; ++ni) {
      const int col = ni * 64 + w * 16 + l15;
#pragma unroll
      for (int r2 = 0; r2 < 4; ++r2) {
        const int row5 = l4 * 4 + r2;
        if (row5 < 5 && col < MF) m = fmaxf(m, accr[ni][r2]);
      }
    }
#pragma unroll
    for (int mask = 1; mask <= 32; mask <<= 1) m = fmaxf(m, __shfl_xor(m, mask, 64));
    if (lane == 0) mxrf[w] = m;
  }
  __syncthreads();
  // ---- rf exp -> rfs; cross-wave q max ----
  {
    const float mxR = fmaxf(fmaxf(mxrf[0], mxrf[1]), fmaxf(mxrf[2], mxrf[3]));
#pragma unroll
    for (int ni = 0; ni < 10; ++ni) {
      const int col = ni * 64 + w * 16 + l15;
#pragma unroll
      for (int r2 = 0; r2 < 4; ++r2) {
        const int row5 = l4 * 4 + r2;
        if (row5 < 5) {
          float val = (col < MF)
              ? RATIO * (__expf(accr[ni][r2] - diag5v[row5] - mxR) + EPS) : 0.f;
          rfs[row5][col] = val;
        }
      }
    }
  }
  if (tid < 32)
    mxAll[tid] = fmaxf(fmaxf(mxs[0][tid], mxs[1][tid]), fmaxf(mxs[2][tid], mxs[3][tid]));
  __syncthreads();
  for (int i = tid; i < 4 * MFP; i += 256) rfs[i / MFP][i % MFP] -= rfs[4][i % MFP];
  __syncthreads();
  // ---- qf exp + 5 weighted sums ----
  float s[2][4][5] = {};
#pragma unroll
  for (int mi = 0; mi < 2; ++mi)
#pragma unroll
    for (int r2 = 0; r2 < 4; ++r2) {
      const int row = mi * 16 + l4 * 4 + r2;
      const float sub = diag[row] + mxAll[row];
#pragma unroll
      for (int ni = 0; ni < 10; ++ni) {
        const int col = ni * 64 + w * 16 + l15;
        const float qfv = RATIO * (__expf(acc[mi][ni][r2] - sub) + EPS);
#pragma unroll
        for (int c = 0; c < 5; ++c) s[mi][r2][c] += qfv * rfs[c][col];
      }
    }
#pragma unroll
  for (int mask = 1; mask <= 8; mask <<= 1)
#pragma unroll
    for (int mi = 0; mi < 2; ++mi)
#pragma unroll
      for (int r2 = 0; r2 < 4; ++r2)
#pragma unroll
        for (int c = 0; c < 5; ++c)
          s[mi][r2][c] += __shfl_xor(s[mi][r2][c], mask, 64);
  if (l15 == 0) {
#pragma unroll
    for (int mi = 0; mi < 2; ++mi)
#pragma unroll
      for (int r2 = 0; r2 < 4; ++r2)
#pragma unroll
        for (int c = 0; c < 5; ++c)
          sred[w][mi * 16 + l4 * 4 + r2][c] = s[mi][r2][c];
  }
  __syncthreads();
  if (tid < 160) {
    const int row = tid / 5, c = tid % 5;
    fdv[row][c] = sred[0][row][c] + sred[1][row][c] + sred[2][row][c] + sred[3][row][c];
  }
  __syncthreads();
  // ---- Dinv per row ----
  if (tid < 32) {
    const int blg = (r0 >> 3) + (tid >> 3);
    const int l = blg % L;
    const int xo = (l < 100) ? (l % 10) : 0;
    const int yo = (l < 100) ? (l / 10) : 10;
    float c0 = 0, c1 = 0, c2 = 0, c3 = 0;
#pragma unroll
    for (int k = 0; k < 49; ++k) {
      const int dx = (k % 7) - 3, dy = (k / 7) - 3;
      const int xp = xo + dx, yp = yo + dy;
      const int df = (dx < 0 ? -dx : dx) + (dy < 0 ? -dy : dy);
      if (xp >= 0 && xp < 10 && yp >= 0 && yp < 10 && df < 4) {
        if (df == 0) c0 += 1.f; else if (df == 1) c1 += 1.f;
        else if (df == 2) c2 += 1.f; else c3 += 1.f;
      }
    }
    const float D = c0 * fdv[tid][0] + c1 * fdv[tid][1] + c2 * fdv[tid][2] +
                    c3 * fdv[tid][3] + (float)L * fdv[tid][4];
    fdv[tid][5] = 1.f / D;
  }
  __syncthreads();
  // ---- gather + normalize + bf16-split (absorbed out_kernel) ----
#pragma unroll
  for (int bl = 0; bl < 4; ++bl) {
    const int blg = (r0 >> 3) + bl;
    const int b = blg / L, l = blg % L;
    const int xo = (l < 100) ? (l % 10) : 0;
    const int yo = (l < 100) ? (l / 10) : 10;
#pragma unroll
    for (int hh = 0; hh < 8; hh += 2) {
      const int h = hh + (tid >> 7), d = tid & 127;
      const int row = bl * 8 + h;
      float o = fdv[row][4] * vsum[(size_t)(b * 8 + h) * DH + d];
      const float* vb = v + (size_t)(b * L) * DIM + h * DH + d;
#pragma unroll
      for (int k = 0; k < 49; ++k) {
        const int dx = (k % 7) - 3, dy = (k / 7) - 3;
        const int xp = xo + dx, yp = yo + dy;
        const int df = (dx < 0 ? -dx : dx) + (dy < 0 ? -dy : dy);
        if (xp >= 0 && xp < 10 && yp >= 0 && yp < 10 && df < 4) {
          const int pos = l + dx + 10 * dy;
          o += fdv[row][df] * vb[(size_t)pos * DIM];
        }
      }
      const float val = o * fdv[row][5];
      bf16_t hi, lo; split2(val, hi, lo);
      const size_t oi = (size_t)(b * L + l) * DIM + h * DH + d;
      attnh[oi] = hi;
      attnl[oi] = lo;
    }
  }
}

}  // namespace

extern "C" void kernel_launch(void* const* d_in, const int* in_sizes, int n_in,
                              void* d_out, int out_size, void* d_ws, size_t ws_size,
                              hipStream_t stream) {
  const float* x    = (const float*)d_in[0];
  const float* Wq   = (const float*)d_in[1];
  const float* bq   = (const float*)d_in[2];
  const float* Wv   = (const float*)d_in[3];
  const float* bv   = (const float*)d_in[4];
  const float* rpe  = (const float*)d_in[5];
  const float* proj = (const float*)d_in[6];
  const float* Wo   = (const float*)d_in[7];
  const float* bo   = (const float*)d_in[8];

  char* p = (char*)d_ws;
  auto alloc = [&](size_t bytes) { char* r = p; p += (bytes + 255) & ~255ull; return r; };
  bf16_t* xh  = (bf16_t*)alloc((size_t)BLP * DIM * 2);
  bf16_t* xl  = (bf16_t*)alloc((size_t)BLP * DIM * 2);
  bf16_t* Wh  = (bf16_t*)alloc((size_t)2 * DIM * DIM * 2);  // Wq rows 0..1023, Wv rows 1024..2047
  bf16_t* Woh = (bf16_t*)alloc((size_t)DIM * DIM * 2);
  bf16_t* ph  = (bf16_t*)alloc((size_t)MFP * DH * 2);
  bf16_t* rh  = (bf16_t*)alloc((size_t)64 * DH * 2);
  bf16_t* rl  = (bf16_t*)alloc((size_t)64 * DH * 2);
  bf16_t* qh  = (bf16_t*)alloc((size_t)BLP * DIM * 2);   // q, later attn
  bf16_t* ql  = (bf16_t*)alloc((size_t)BLP * DIM * 2);
  float*  v   = (float*)alloc((size_t)BL * DIM * 4);
  float*  vsm = (float*)alloc((size_t)BH * DH * 4);

  split_all<<<(NTOT + 255) / 256, 256, 0, stream>>>(x, proj, rpe, Wq, Wv, Wo,
                                                    xh, xl, ph, rh, rl,
                                                    Wh, Woh, qh, ql, vsm);
  // fused q+v projection: N=2048, 2-term, BK=64 (416 blocks) + vsum atomics
  gemm64<1><<<dim3(32, 13), 256, 0, stream>>>(xh, xl, Wh, bq, bv, v, qh, ql, vsm);
  // fused dd + feature reductions + gather-out (202 blocks)
  qf3_kernel<<<202, 256, 0, stream>>>(qh, ql, rh, rl, ph, rpe, v, vsm, qh, ql);
  // output projection: 2-term, BK=64 (208 blocks)
  gemm64<0><<<dim3(16, 13), 256, 0, stream>>>(qh, ql, Woh, bo, nullptr,
                                              (float*)d_out, nullptr, nullptr, nullptr);
}

// Round 12
// 76.781 us; speedup vs baseline: 1.7991x; 1.7991x over previous
//
#include <hip/hip_runtime.h>
#include <math.h>

namespace {

typedef __bf16 bf16_t;
typedef bf16_t bf16x8 __attribute__((ext_vector_type(8)));
typedef bf16_t bf16x4 __attribute__((ext_vector_type(4)));
typedef float f32x4 __attribute__((ext_vector_type(4)));

constexpr int B = 8, L = 101, DIM = 1024, H = 8, DH = 128, MF = 621, MFP = 640;
constexpr int BL = B * L;    // 808
constexpr int BLP = 832;     // padded rows for GEMM A
constexpr int BH = B * H;    // 64
constexpr int RR = BL * H;   // 6464

constexpr float DN    = 0.29730177875068026f;   // 128^-0.25
constexpr float DN2   = 0.08838834764831845f;   // 128^-0.5
constexpr float RATIO = 0.04012861672f;         // 621^-0.5
constexpr float EPS   = 1e-4f;

// split_all segment sizes (bf16x4 / float4 units)
constexpr int NX = BL * DIM / 4;    // 206848 (x -> xh only)
constexpr int NP = MFP * 32;        // 20480  (proj -> ph only)
constexpr int NR = 64 * DH / 4;     // 2048   (rpe, padded to 64 rows, split)
constexpr int NW = DIM * DIM / 4;   // 262144
constexpr int NZ = 3 * (BLP - BL) * DIM / 4;  // 18432 pad-zero units (xh,qh,ql)
constexpr int NV = BH * DH / 4;     // 2048 (vsum zero)
constexpr int NTOT = NX + NP + NR + 3 * NW + NZ + NV;

__device__ __forceinline__ f32x4 mfma16(bf16x8 a, bf16x8 b, f32x4 c) {
  return __builtin_amdgcn_mfma_f32_16x16x32_bf16(a, b, c, 0, 0, 0);
}

__device__ __forceinline__ void split2(float f, bf16_t& h, bf16_t& l) {
  h = (bf16_t)f;
  l = (bf16_t)(f - (float)h);
}

__device__ __forceinline__ void gload_lds16(const bf16_t* g, bf16_t* l) {
  __builtin_amdgcn_global_load_lds(
      (const __attribute__((address_space(1))) void*)g,
      (__attribute__((address_space(3))) void*)l, 16, 0, 0);
}

// ---------- one-shot convert/split of everything (+ vsum zero) ----------
__global__ __launch_bounds__(256) void split_all(const float* __restrict__ x,
                                                 const float* __restrict__ proj,
                                                 const float* __restrict__ rpe,
                                                 const float* __restrict__ Wq,
                                                 const float* __restrict__ Wv,
                                                 const float* __restrict__ Wo,
                                                 bf16_t* __restrict__ xh,
                                                 bf16_t* __restrict__ ph,
                                                 bf16_t* __restrict__ rh, bf16_t* __restrict__ rl,
                                                 bf16_t* __restrict__ Wh,
                                                 bf16_t* __restrict__ Woh,
                                                 bf16_t* __restrict__ qh, bf16_t* __restrict__ ql,
                                                 float* __restrict__ vsum) {
  const int u = blockIdx.x * 256 + threadIdx.x;
  if (u >= NTOT) return;
  auto emit2 = [](const float* s4, float sc, bf16_t* dh, bf16_t* dl, size_t off) {
    float4 f = *(const float4*)s4;
    bf16x4 hv, lv; bf16_t h, l;
    split2(f.x * sc, h, l); hv[0] = h; lv[0] = l;
    split2(f.y * sc, h, l); hv[1] = h; lv[1] = l;
    split2(f.z * sc, h, l); hv[2] = h; lv[2] = l;
    split2(f.w * sc, h, l); hv[3] = h; lv[3] = l;
    *(bf16x4*)(dh + off) = hv;
    *(bf16x4*)(dl + off) = lv;
  };
  auto emit1 = [](const float* s4, float sc, bf16_t* dh, size_t off) {
    float4 f = *(const float4*)s4;
    bf16x4 hv;
    hv[0] = (bf16_t)(f.x * sc); hv[1] = (bf16_t)(f.y * sc);
    hv[2] = (bf16_t)(f.z * sc); hv[3] = (bf16_t)(f.w * sc);
    *(bf16x4*)(dh + off) = hv;
  };
  int t = u;
  if (t < NX) { emit1(x + (size_t)t * 4, 1.f, xh, (size_t)t * 4); return; }
  t -= NX;
  if (t < NP) {
    if ((t >> 5) < MF) emit1(proj + (size_t)t * 4, DN, ph, (size_t)t * 4);
    else { bf16x4 z = {}; *(bf16x4*)(ph + (size_t)t * 4) = z; }
    return;
  }
  t -= NP;
  if (t < NR) {
    if (t < 5 * DH / 4) emit2(rpe + (size_t)t * 4, 1.f, rh, rl, (size_t)t * 4);
    else { bf16x4 z = {}; *(bf16x4*)(rh + (size_t)t * 4) = z; *(bf16x4*)(rl + (size_t)t * 4) = z; }
    return;
  }
  t -= NR;
  if (t < NW) { emit1(Wq + (size_t)t * 4, 1.f, Wh, (size_t)t * 4); return; }
  t -= NW;
  if (t < NW) { emit1(Wv + (size_t)t * 4, 1.f, Wh, (size_t)(t + NW) * 4); return; }
  t -= NW;
  if (t < NW) { emit1(Wo + (size_t)t * 4, 1.f, Woh, (size_t)t * 4); return; }
  t -= NW;
  if (t < NZ) {  // zero pads rows 808..831 of xh,qh,ql
    const int buf = t / 6144, o = t % 6144;
    bf16_t* dst = (buf == 0) ? xh : (buf == 1) ? qh : ql;
    bf16x4 z = {};
    *(bf16x4*)(dst + (size_t)BL * DIM + (size_t)o * 4) = z;
    return;
  }
  t -= NZ;
  ((float4*)vsum)[t] = make_float4(0.f, 0.f, 0.f, 0.f);
}

// ---------- BK=64 LDS-staged MFMA GEMM, block tile 64x64, 4 waves 32x32 ----------
// AT=1: C = A @ B^T (A plain bf16).  AT=2: C = (Ah+Al) @ B^T.
// MODE 0: f32 out + bias0 (o-proj). MODE 1: qv — q bf16-split / v f32 + vsum atomics.
template<int MODE, int AT>
__global__ __launch_bounds__(256) void gemm64(const bf16_t* __restrict__ Ah,
                                              const bf16_t* __restrict__ Al,
                                              const bf16_t* __restrict__ Bh,
                                              const float* __restrict__ bias0,
                                              const float* __restrict__ bias1,
                                              float* __restrict__ Cf,
                                              bf16_t* __restrict__ Ch,
                                              bf16_t* __restrict__ Cl,
                                              float* __restrict__ vsum) {
  constexpr int K = 1024, BK = 64, NK = K / BK;   // 16 steps
  constexpr int NT = AT + 1;
  __shared__ bf16_t lds[2][NT][64 * 64];
  const int tid = threadIdx.x;
  const int w = tid >> 6, lane = tid & 63;
  const int wr = w >> 1, wc = w & 1;
  const int l15 = lane & 15, l4 = lane >> 4;
  const int rowBase = blockIdx.y * 64, colBase = blockIdx.x * 64;
  const int r8 = lane >> 3;                 // 0..7
  const int cs = (lane & 7) ^ r8;           // pre-swizzled source col16 group
  const bf16_t* src;
  int grow0, ti, dst0;
  if (AT == 2) {
    src = (w == 0) ? Ah : (w == 1) ? Al : Bh;
    grow0 = (w < 2) ? rowBase : colBase + ((w == 3) ? 32 : 0);
    ti = (w < 2) ? w : 2;
    dst0 = (w == 3) ? 32 * 64 : 0;
  } else {
    src = (w < 2) ? Ah : Bh;
    grow0 = ((w < 2) ? rowBase : colBase) + ((w & 1) ? 32 : 0);
    ti = (w < 2) ? 0 : 1;
    dst0 = (w & 1) ? 32 * 64 : 0;
  }
  const bf16_t* srcL = src + (size_t)(grow0 + r8) * K + cs * 8;
  auto STAGE = [&](int bf, int k0) {
    if (AT == 2 && w < 2) {
#pragma unroll
      for (int j = 0; j < 8; ++j)
        gload_lds16(srcL + (size_t)(8 * j) * K + k0, &lds[bf][ti][j * 512]);
    } else {
#pragma unroll
      for (int j = 0; j < 4; ++j)
        gload_lds16(srcL + (size_t)(8 * j) * K + k0, &lds[bf][ti][dst0 + j * 512]);
    }
  };
  const int ra0 = wr * 32 + l15, ra1 = ra0 + 16;
  const int rb0 = wc * 32 + l15, rb1 = rb0 + 16;
  constexpr int bt = (AT == 1) ? 1 : 2;
  auto TADDR = [](int row, int kg) { return row * 64 + (((kg) ^ (row & 7)) << 3); };
  f32x4 acc[2][2] = {};
  STAGE(0, 0);
  __syncthreads();
  int bf = 0;
  for (int ks = 0; ks < NK; ++ks) {
    if (ks + 1 < NK) STAGE(bf ^ 1, (ks + 1) * BK);
#pragma unroll
    for (int subk = 0; subk < 2; ++subk) {
      const int kg = subk * 4 + l4;
      bf16x8 a0h = *(const bf16x8*)&lds[bf][0][TADDR(ra0, kg)];
      bf16x8 a1h = *(const bf16x8*)&lds[bf][0][TADDR(ra1, kg)];
      bf16x8 b0  = *(const bf16x8*)&lds[bf][bt][TADDR(rb0, kg)];
      bf16x8 b1  = *(const bf16x8*)&lds[bf][bt][TADDR(rb1, kg)];
      acc[0][0] = mfma16(a0h, b0, acc[0][0]);
      acc[0][1] = mfma16(a0h, b1, acc[0][1]);
      acc[1][0] = mfma16(a1h, b0, acc[1][0]);
      acc[1][1] = mfma16(a1h, b1, acc[1][1]);
      if (AT == 2) {
        bf16x8 a0l = *(const bf16x8*)&lds[bf][1][TADDR(ra0, kg)];
        bf16x8 a1l = *(const bf16x8*)&lds[bf][1][TADDR(ra1, kg)];
        acc[0][0] = mfma16(a0l, b0, acc[0][0]);
        acc[0][1] = mfma16(a0l, b1, acc[0][1]);
        acc[1][0] = mfma16(a1l, b0, acc[1][0]);
        acc[1][1] = mfma16(a1l, b1, acc[1][1]);
      }
    }
    __syncthreads();
    bf ^= 1;
  }
#pragma unroll
  for (int ni = 0; ni < 2; ++ni) {
    const int col = colBase + wc * 32 + ni * 16 + l15;
#pragma unroll
    for (int mi = 0; mi < 2; ++mi) {
      float vpart = 0.f;
      int curb = -1;
#pragma unroll
      for (int r2 = 0; r2 < 4; ++r2) {
        const int row = rowBase + wr * 32 + mi * 16 + l4 * 4 + r2;
        if (row < BL) {
          if (MODE == 0) {
            Cf[(size_t)row * 1024 + col] = acc[mi][ni][r2] + bias0[col];
          } else {
            if (col < 1024) {
              float val = acc[mi][ni][r2] + bias0[col];
              bf16_t h, lo; split2(val, h, lo);
              Ch[(size_t)row * 1024 + col] = h;
              Cl[(size_t)row * 1024 + col] = lo;
            } else {
              const int vcol = col - 1024;
              const float val = acc[mi][ni][r2] + bias1[vcol];
              Cf[(size_t)row * 1024 + vcol] = val;
              const int b = row / L;
              if (b != curb) {
                if (curb >= 0)
                  atomicAdd(&vsum[(size_t)(curb * 8) * DH + vcol], vpart);
                curb = b; vpart = 0.f;
              }
              vpart += val;
            }
          }
        }
      }
      if (MODE == 1 && curb >= 0)
        atomicAdd(&vsum[(size_t)(curb * 8) * DH + (col - 1024)], vpart);
    }
  }
}

// ---------- qf3: fused dd-GEMM (in-register) + rf + maxes + exp + 5 reductions ----------
// Block = 32 q-rows x 640 cols; grid 202. Writes fd[r][0..4].
__global__ __launch_bounds__(256) void qf3_kernel(const bf16_t* __restrict__ qh,
                                                  const bf16_t* __restrict__ ql,
                                                  const bf16_t* __restrict__ rh,
                                                  const bf16_t* __restrict__ rl,
                                                  const bf16_t* __restrict__ ph,
                                                  const float* __restrict__ rpe,
                                                  float* __restrict__ fd) {
  const int tid = threadIdx.x;
  __shared__ bf16_t Ahl[2][64 * 128];   // [h,l][row*128]; rows 0..31 q, 32..63 rf(pad)
  __shared__ bf16_t Bch[2][64 * 128];   // [dbuf] chunk of ph
  __shared__ float rfs[5][MFP];
  __shared__ float diag[32];
  __shared__ float diag5v[8];
  __shared__ float mxs[4][32];
  __shared__ float mxAll[32];
  __shared__ float mxrf[4];
  __shared__ float sred[4][32][5];
  const int w = tid >> 6, lane = tid & 63;
  const int l15 = lane & 15, l4 = lane >> 4;
  const int r0 = blockIdx.x * 32;
  const int r4 = lane >> 4;        // 0..3
  const int cg = lane & 15;        // dest col16
  // ---- A stage (once) ----
  {
    const bf16_t* srcA = (w == 0) ? qh : (w == 1) ? ql : (w == 2) ? rh : rl;
    const int arow0 = (w < 2) ? r0 : 0;
    bf16_t* dstA = &Ahl[w & 1][(w >= 2 ? 32 : 0) * 128];
    const bf16_t* peA = srcA + (size_t)(arow0 + r4) * DH + ((cg ^ r4) << 3);
    const bf16_t* poA = srcA + (size_t)(arow0 + r4) * DH + ((cg ^ r4 ^ 4) << 3);
#pragma unroll
    for (int j = 0; j < 8; ++j)
      gload_lds16(((j & 1) ? poA : peA) + (size_t)(4 * j) * DH, dstA + j * 512);
  }
  // ---- B chunk stage ----
  const bf16_t* peB = ph + (size_t)(w * 16 + r4) * DH + ((cg ^ r4) << 3);
  const bf16_t* poB = ph + (size_t)(w * 16 + r4) * DH + ((cg ^ r4 ^ 4) << 3);
  auto STAGE_B = [&](int buf, int c) {
    const size_t coff = (size_t)c * 64 * DH;
#pragma unroll
    for (int j = 0; j < 4; ++j)
      gload_lds16(((j & 1) ? poB : peB) + coff + (size_t)(4 * j) * DH,
                  &Bch[buf][(w * 16 + j * 4) * 128]);
  };
  // ---- diag / diag5v ----
  {
    const int row = tid >> 3, ch = tid & 7;
    const size_t base = (size_t)(r0 + row) * DH + ch * 16;
    float s = 0.f;
#pragma unroll
    for (int t = 0; t < 2; ++t) {
      bf16x8 vh = *(const bf16x8*)(qh + base + t * 8);
      bf16x8 vl = *(const bf16x8*)(ql + base + t * 8);
#pragma unroll
      for (int e = 0; e < 8; ++e) {
        float f = (float)vh[e] + (float)vl[e];
        s += f * f;
      }
    }
    s += __shfl_xor(s, 1, 64); s += __shfl_xor(s, 2, 64); s += __shfl_xor(s, 4, 64);
    if (ch == 0) diag[row] = (0.5f * DN2) * s;
  }
  if (tid < 40) {
    const int row = tid >> 3, ch = tid & 7;
    float s = 0.f;
#pragma unroll
    for (int e = 0; e < 16; ++e) { float f = rpe[row * DH + ch * 16 + e]; s += f * f; }
    s += __shfl_xor(s, 1, 64); s += __shfl_xor(s, 2, 64); s += __shfl_xor(s, 4, 64);
    if (ch == 0) diag5v[row] = (0.5f * DN2) * s;
  }
  // ---- main loop: 10 chunks x 4 k-steps ----
  auto TADDR = [](int row, int kg) { return row * 128 + (((kg) ^ (row & 7)) << 3); };
  f32x4 acc[2][10] = {};
  f32x4 accr[10] = {};
  STAGE_B(0, 0);
  __syncthreads();
  int buf = 0;
#pragma unroll
  for (int c = 0; c < 10; ++c) {
    if (c + 1 < 10) STAGE_B(buf ^ 1, c + 1);
#pragma unroll
    for (int ks = 0; ks < 4; ++ks) {
      const int kg = ks * 4 + l4;
      bf16x8 a0h = *(const bf16x8*)&Ahl[0][TADDR(l15, kg)];
      bf16x8 a0l = *(const bf16x8*)&Ahl[1][TADDR(l15, kg)];
      bf16x8 a1h = *(const bf16x8*)&Ahl[0][TADDR(16 + l15, kg)];
      bf16x8 a1l = *(const bf16x8*)&Ahl[1][TADDR(16 + l15, kg)];
      bf16x8 arh = *(const bf16x8*)&Ahl[0][TADDR(32 + l15, kg)];
      bf16x8 arl = *(const bf16x8*)&Ahl[1][TADDR(32 + l15, kg)];
      bf16x8 bb  = *(const bf16x8*)&Bch[buf][TADDR(w * 16 + l15, kg)];
      acc[0][c] = mfma16(a0h, bb, acc[0][c]);
      acc[0][c] = mfma16(a0l, bb, acc[0][c]);
      acc[1][c] = mfma16(a1h, bb, acc[1][c]);
      acc[1][c] = mfma16(a1l, bb, acc[1][c]);
      accr[c]   = mfma16(arh, bb, accr[c]);
      accr[c]   = mfma16(arl, bb, accr[c]);
    }
    __syncthreads();
    buf ^= 1;
  }
  // ---- q per-row max ----
  float pm[2][4];
#pragma unroll
  for (int mi = 0; mi < 2; ++mi)
#pragma unroll
    for (int r2 = 0; r2 < 4; ++r2) {
      float m = -3.4e38f;
#pragma unroll
      for (int ni = 0; ni < 10; ++ni) {
        const int col = ni * 64 + w * 16 + l15;
        float vv = (col < MF) ? acc[mi][ni][r2] : -3.4e38f;
        m = fmaxf(m, vv);
      }
      pm[mi][r2] = m;
    }
#pragma unroll
  for (int mask = 1; mask <= 8; mask <<= 1)
#pragma unroll
    for (int mi = 0; mi < 2; ++mi)
#pragma unroll
      for (int r2 = 0; r2 < 4; ++r2)
        pm[mi][r2] = fmaxf(pm[mi][r2], __shfl_xor(pm[mi][r2], mask, 64));
  if (l15 == 0) {
#pragma unroll
    for (int mi = 0; mi < 2; ++mi)
#pragma unroll
      for (int r2 = 0; r2 < 4; ++r2)
        mxs[w][mi * 16 + l4 * 4 + r2] = pm[mi][r2];
  }
  // ---- rf global max ----
  {
    float m = -3.4e38f;
#pragma unroll
    for (int ni = 0; ni < 10; ++ni) {
      const int col = ni * 64 + w * 16 + l15;
#pragma unroll
      for (int r2 = 0; r2 < 4; ++r2) {
        const int row5 = l4 * 4 + r2;
        if (row5 < 5 && col < MF) m = fmaxf(m, accr[ni][r2]);
      }
    }
#pragma unroll
    for (int mask = 1; mask <= 32; mask <<= 1) m = fmaxf(m, __shfl_xor(m, mask, 64));
    if (lane == 0) mxrf[w] = m;
  }
  __syncthreads();
  // ---- rf exp -> rfs ----
  {
    const float mxR = fmaxf(fmaxf(mxrf[0], mxrf[1]), fmaxf(mxrf[2], mxrf[3]));
#pragma unroll
    for (int ni = 0; ni < 10; ++ni) {
      const int col = ni * 64 + w * 16 + l15;
#pragma unroll
      for (int r2 = 0; r2 < 4; ++r2) {
        const int row5 = l4 * 4 + r2;
        if (row5 < 5) {
          float val = (col < MF)
              ? RATIO * (__expf(accr[ni][r2] - diag5v[row5] - mxR) + EPS) : 0.f;
          rfs[row5][col] = val;
        }
      }
    }
  }
  if (tid < 32)
    mxAll[tid] = fmaxf(fmaxf(mxs[0][tid], mxs[1][tid]), fmaxf(mxs[2][tid], mxs[3][tid]));
  __syncthreads();
  for (int i = tid; i < 4 * MFP; i += 256) rfs[i / MFP][i % MFP] -= rfs[4][i % MFP];
  __syncthreads();
  // ---- qf exp + 5 weighted sums ----
  float s[2][4][5] = {};
#pragma unroll
  for (int mi = 0; mi < 2; ++mi)
#pragma unroll
    for (int r2 = 0; r2 < 4; ++r2) {
      const int row = mi * 16 + l4 * 4 + r2;
      const float sub = diag[row] + mxAll[row];
#pragma unroll
      for (int ni = 0; ni < 10; ++ni) {
        const int col = ni * 64 + w * 16 + l15;
        const float qfv = RATIO * (__expf(acc[mi][ni][r2] - sub) + EPS);
#pragma unroll
        for (int c = 0; c < 5; ++c) s[mi][r2][c] += qfv * rfs[c][col];
      }
    }
#pragma unroll
  for (int mask = 1; mask <= 8; mask <<= 1)
#pragma unroll
    for (int mi = 0; mi < 2; ++mi)
#pragma unroll
      for (int r2 = 0; r2 < 4; ++r2)
#pragma unroll
        for (int c = 0; c < 5; ++c)
          s[mi][r2][c] += __shfl_xor(s[mi][r2][c], mask, 64);
  if (l15 == 0) {
#pragma unroll
    for (int mi = 0; mi < 2; ++mi)
#pragma unroll
      for (int r2 = 0; r2 < 4; ++r2)
#pragma unroll
        for (int c = 0; c < 5; ++c)
          sred[w][mi * 16 + l4 * 4 + r2][c] = s[mi][r2][c];
  }
  __syncthreads();
  if (tid < 160) {
    const int row = tid / 5, c = tid % 5;
    fd[(size_t)(r0 + row) * 8 + c] =
        sred[0][row][c] + sred[1][row][c] + sred[2][row][c] + sred[3][row][c];
  }
}

// ---------- gather + normalize + bf16-split of attn ----------
__global__ __launch_bounds__(256) void out_kernel(const float* __restrict__ fd,
                                                  const float* __restrict__ v,
                                                  const float* __restrict__ vsum,
                                                  bf16_t* __restrict__ attnh,
                                                  bf16_t* __restrict__ attnl) {
  const int tid = threadIdx.x;
  const int sub = tid >> 7, d = tid & 127;
  const int bh = blockIdx.y, b = bh >> 3, h = bh & 7;
  const int l = blockIdx.x * 2 + sub;
  if (l >= L) return;
  const size_t r = (size_t)(b * L + l) * H + h;
  const float q0 = fd[r * 8 + 0], q1 = fd[r * 8 + 1], q2 = fd[r * 8 + 2],
              q3 = fd[r * 8 + 3], sM = fd[r * 8 + 4];
  float o = sM * vsum[(size_t)bh * DH + d];
  float c0 = 0, c1 = 0, c2 = 0, c3 = 0;
  const int xo = (l < 100) ? (l % 10) : 0;
  const int yo = (l < 100) ? (l / 10) : 10;
#pragma unroll
  for (int k = 0; k < 49; ++k) {
    const int dx = (k % 7) - 3, dy = (k / 7) - 3;
    const int xp = xo + dx, yp = yo + dy;
    const int df = (dx < 0 ? -dx : dx) + (dy < 0 ? -dy : dy);
    if (xp >= 0 && xp < 10 && yp >= 0 && yp < 10 && df < 4) {
      float qq;
      if (df == 0)      { c0 += 1.f; qq = q0; }
      else if (df == 1) { c1 += 1.f; qq = q1; }
      else if (df == 2) { c2 += 1.f; qq = q2; }
      else              { c3 += 1.f; qq = q3; }
      const int pos = l + dx + 10 * dy;
      o += qq * v[(size_t)(b * L + pos) * DIM + h * DH + d];
    }
  }
  const float D = c0 * q0 + c1 * q1 + c2 * q2 + c3 * q3 + (float)L * sM;
  const float val = o / D;
  bf16_t hi, lo; split2(val, hi, lo);
  const size_t oi = (size_t)(b * L + l) * DIM + h * DH + d;
  attnh[oi] = hi;
  attnl[oi] = lo;
}

}  // namespace

extern "C" void kernel_launch(void* const* d_in, const int* in_sizes, int n_in,
                              void* d_out, int out_size, void* d_ws, size_t ws_size,
                              hipStream_t stream) {
  const float* x    = (const float*)d_in[0];
  const float* Wq   = (const float*)d_in[1];
  const float* bq   = (const float*)d_in[2];
  const float* Wv   = (const float*)d_in[3];
  const float* bv   = (const float*)d_in[4];
  const float* rpe  = (const float*)d_in[5];
  const float* proj = (const float*)d_in[6];
  const float* Wo   = (const float*)d_in[7];
  const float* bo   = (const float*)d_in[8];

  char* p = (char*)d_ws;
  auto alloc = [&](size_t bytes) { char* r = p; p += (bytes + 255) & ~255ull; return r; };
  bf16_t* xh  = (bf16_t*)alloc((size_t)BLP * DIM * 2);
  bf16_t* Wh  = (bf16_t*)alloc((size_t)2 * DIM * DIM * 2);  // Wq rows 0..1023, Wv rows 1024..2047
  bf16_t* Woh = (bf16_t*)alloc((size_t)DIM * DIM * 2);
  bf16_t* ph  = (bf16_t*)alloc((size_t)MFP * DH * 2);
  bf16_t* rh  = (bf16_t*)alloc((size_t)64 * DH * 2);
  bf16_t* rl  = (bf16_t*)alloc((size_t)64 * DH * 2);
  bf16_t* qh  = (bf16_t*)alloc((size_t)BLP * DIM * 2);   // q, later attn
  bf16_t* ql  = (bf16_t*)alloc((size_t)BLP * DIM * 2);
  float*  v   = (float*)alloc((size_t)BL * DIM * 4);
  float*  fd  = (float*)alloc((size_t)RR * 8 * 4);
  float*  vsm = (float*)alloc((size_t)BH * DH * 4);

  split_all<<<(NTOT + 255) / 256, 256, 0, stream>>>(x, proj, rpe, Wq, Wv, Wo,
                                                    xh, ph, rh, rl,
                                                    Wh, Woh, qh, ql, vsm);
  // fused q+v projection: N=2048, 1-term A, BK=64 (416 blocks) + vsum atomics
  gemm64<1, 1><<<dim3(32, 13), 256, 0, stream>>>(xh, nullptr, Wh, bq, bv,
                                                 v, qh, ql, vsm);
  // fused dd + feature reductions (202 blocks)
  qf3_kernel<<<202, 256, 0, stream>>>(qh, ql, rh, rl, ph, rpe, fd);
  out_kernel<<<dim3((L + 1) / 2, BH), 256, 0, stream>>>(fd, v, vsm, qh, ql);
  // output projection: 2-term A, BK=64 (208 blocks)
  gemm64<0, 2><<<dim3(16, 13), 256, 0, stream>>>(qh, ql, Woh, bo, nullptr,
                                                 (float*)d_out, nullptr, nullptr, nullptr);
}

// Round 14
// 71.558 us; speedup vs baseline: 1.9304x; 1.0730x over previous
//
#include <hip/hip_runtime.h>
#include <math.h>

namespace {

typedef __bf16 bf16_t;
typedef bf16_t bf16x8 __attribute__((ext_vector_type(8)));
typedef bf16_t bf16x4 __attribute__((ext_vector_type(4)));
typedef float f32x4 __attribute__((ext_vector_type(4)));

constexpr int B = 8, L = 101, DIM = 1024, H = 8, DH = 128, MF = 621, MFP = 640;
constexpr int BL = B * L;    // 808
constexpr int BLP = 832;     // padded rows for GEMM A
constexpr int BH = B * H;    // 64
constexpr int RR = BL * H;   // 6464

constexpr float DN    = 0.29730177875068026f;   // 128^-0.25
constexpr float DN2   = 0.08838834764831845f;   // 128^-0.5
constexpr float RATIO = 0.04012861672f;         // 621^-0.5
constexpr float EPS   = 1e-4f;

// split_all segment sizes (bf16x4 / float4 units)
constexpr int NX = BL * DIM / 4;    // 206848 (x -> xh only)
constexpr int NP = MFP * 32;        // 20480  (proj -> ph only)
constexpr int NR = 64 * DH / 4;     // 2048   (rpe, padded to 64 rows, split)
constexpr int NW = DIM * DIM / 4;   // 262144
constexpr int NZ = 3 * (BLP - BL) * DIM / 4;  // 18432 pad-zero units (xh,qh,ql)
constexpr int NV = BH * DH / 4;     // 2048 (vsum zero)
constexpr int NTOT = NX + NP + NR + 3 * NW + NZ + NV;

__device__ __forceinline__ f32x4 mfma16(bf16x8 a, bf16x8 b, f32x4 c) {
  return __builtin_amdgcn_mfma_f32_16x16x32_bf16(a, b, c, 0, 0, 0);
}

__device__ __forceinline__ void split2(float f, bf16_t& h, bf16_t& l) {
  h = (bf16_t)f;
  l = (bf16_t)(f - (float)h);
}

__device__ __forceinline__ void gload_lds16(const bf16_t* g, bf16_t* l) {
  __builtin_amdgcn_global_load_lds(
      (const __attribute__((address_space(1))) void*)g,
      (__attribute__((address_space(3))) void*)l, 16, 0, 0);
}

// ---------- one-shot convert/split of everything (+ vsum zero) ----------
__global__ __launch_bounds__(256) void split_all(const float* __restrict__ x,
                                                 const float* __restrict__ proj,
                                                 const float* __restrict__ rpe,
                                                 const float* __restrict__ Wq,
                                                 const float* __restrict__ Wv,
                                                 const float* __restrict__ Wo,
                                                 bf16_t* __restrict__ xh,
                                                 bf16_t* __restrict__ ph,
                                                 bf16_t* __restrict__ rh, bf16_t* __restrict__ rl,
                                                 bf16_t* __restrict__ Wh,
                                                 bf16_t* __restrict__ Woh,
                                                 bf16_t* __restrict__ qh, bf16_t* __restrict__ ql,
                                                 float* __restrict__ vsum) {
  const int u = blockIdx.x * 256 + threadIdx.x;
  if (u >= NTOT) return;
  auto emit2 = [](const float* s4, float sc, bf16_t* dh, bf16_t* dl, size_t off) {
    float4 f = *(const float4*)s4;
    bf16x4 hv, lv; bf16_t h, l;
    split2(f.x * sc, h, l); hv[0] = h; lv[0] = l;
    split2(f.y * sc, h, l); hv[1] = h; lv[1] = l;
    split2(f.z * sc, h, l); hv[2] = h; lv[2] = l;
    split2(f.w * sc, h, l); hv[3] = h; lv[3] = l;
    *(bf16x4*)(dh + off) = hv;
    *(bf16x4*)(dl + off) = lv;
  };
  auto emit1 = [](const float* s4, float sc, bf16_t* dh, size_t off) {
    float4 f = *(const float4*)s4;
    bf16x4 hv;
    hv[0] = (bf16_t)(f.x * sc); hv[1] = (bf16_t)(f.y * sc);
    hv[2] = (bf16_t)(f.z * sc); hv[3] = (bf16_t)(f.w * sc);
    *(bf16x4*)(dh + off) = hv;
  };
  int t = u;
  if (t < NX) { emit1(x + (size_t)t * 4, 1.f, xh, (size_t)t * 4); return; }
  t -= NX;
  if (t < NP) {
    if ((t >> 5) < MF) emit1(proj + (size_t)t * 4, DN, ph, (size_t)t * 4);
    else { bf16x4 z = {}; *(bf16x4*)(ph + (size_t)t * 4) = z; }
    return;
  }
  t -= NP;
  if (t < NR) {
    if (t < 5 * DH / 4) emit2(rpe + (size_t)t * 4, 1.f, rh, rl, (size_t)t * 4);
    else { bf16x4 z = {}; *(bf16x4*)(rh + (size_t)t * 4) = z; *(bf16x4*)(rl + (size_t)t * 4) = z; }
    return;
  }
  t -= NR;
  if (t < NW) { emit1(Wq + (size_t)t * 4, 1.f, Wh, (size_t)t * 4); return; }
  t -= NW;
  if (t < NW) { emit1(Wv + (size_t)t * 4, 1.f, Wh, (size_t)(t + NW) * 4); return; }
  t -= NW;
  if (t < NW) { emit1(Wo + (size_t)t * 4, 1.f, Woh, (size_t)t * 4); return; }
  t -= NW;
  if (t < NZ) {  // zero pads rows 808..831 of xh,qh,ql
    const int buf = t / 6144, o = t % 6144;
    bf16_t* dst = (buf == 0) ? xh : (buf == 1) ? qh : ql;
    bf16x4 z = {};
    *(bf16x4*)(dst + (size_t)BL * DIM + (size_t)o * 4) = z;
    return;
  }
  t -= NZ;
  ((float4*)vsum)[t] = make_float4(0.f, 0.f, 0.f, 0.f);
}

// ---------- BK=64 LDS-staged MFMA GEMM, block tile 64x64, 4 waves 32x32 ----------
// AT=1: C = A @ B^T (A plain bf16).  AT=2: C = (Ah+Al) @ B^T.
// MODE 0: f32 out + bias0 (o-proj). MODE 1: qv — q bf16-split / v f32 + vsum atomics.
template<int MODE, int AT>
__global__ __launch_bounds__(256) void gemm64(const bf16_t* __restrict__ Ah,
                                              const bf16_t* __restrict__ Al,
                                              const bf16_t* __restrict__ Bh,
                                              const float* __restrict__ bias0,
                                              const float* __restrict__ bias1,
                                              float* __restrict__ Cf,
                                              bf16_t* __restrict__ Ch,
                                              bf16_t* __restrict__ Cl,
                                              float* __restrict__ vsum) {
  constexpr int K = 1024, BK = 64, NK = K / BK;   // 16 steps
  constexpr int NT = AT + 1;
  __shared__ bf16_t lds[2][NT][64 * 64];
  const int tid = threadIdx.x;
  const int w = tid >> 6, lane = tid & 63;
  const int wr = w >> 1, wc = w & 1;
  const int l15 = lane & 15, l4 = lane >> 4;
  const int rowBase = blockIdx.y * 64, colBase = blockIdx.x * 64;
  const int r8 = lane >> 3;                 // 0..7
  const int cs = (lane & 7) ^ r8;           // pre-swizzled source col16 group
  const bf16_t* src;
  int grow0, ti, dst0;
  if (AT == 2) {
    src = (w == 0) ? Ah : (w == 1) ? Al : Bh;
    grow0 = (w < 2) ? rowBase : colBase + ((w == 3) ? 32 : 0);
    ti = (w < 2) ? w : 2;
    dst0 = (w == 3) ? 32 * 64 : 0;
  } else {
    src = (w < 2) ? Ah : Bh;
    grow0 = ((w < 2) ? rowBase : colBase) + ((w & 1) ? 32 : 0);
    ti = (w < 2) ? 0 : 1;
    dst0 = (w & 1) ? 32 * 64 : 0;
  }
  const bf16_t* srcL = src + (size_t)(grow0 + r8) * K + cs * 8;
  auto STAGE = [&](int bf, int k0) {
    if (AT == 2 && w < 2) {
#pragma unroll
      for (int j = 0; j < 8; ++j)
        gload_lds16(srcL + (size_t)(8 * j) * K + k0, &lds[bf][ti][j * 512]);
    } else {
#pragma unroll
      for (int j = 0; j < 4; ++j)
        gload_lds16(srcL + (size_t)(8 * j) * K + k0, &lds[bf][ti][dst0 + j * 512]);
    }
  };
  const int ra0 = wr * 32 + l15, ra1 = ra0 + 16;
  const int rb0 = wc * 32 + l15, rb1 = rb0 + 16;
  constexpr int bt = (AT == 1) ? 1 : 2;
  auto TADDR = [](int row, int kg) { return row * 64 + (((kg) ^ (row & 7)) << 3); };
  f32x4 acc[2][2] = {};
  STAGE(0, 0);
  __syncthreads();
  int bf = 0;
  for (int ks = 0; ks < NK; ++ks) {
    if (ks + 1 < NK) STAGE(bf ^ 1, (ks + 1) * BK);
#pragma unroll
    for (int subk = 0; subk < 2; ++subk) {
      const int kg = subk * 4 + l4;
      bf16x8 a0h = *(const bf16x8*)&lds[bf][0][TADDR(ra0, kg)];
      bf16x8 a1h = *(const bf16x8*)&lds[bf][0][TADDR(ra1, kg)];
      bf16x8 b0  = *(const bf16x8*)&lds[bf][bt][TADDR(rb0, kg)];
      bf16x8 b1  = *(const bf16x8*)&lds[bf][bt][TADDR(rb1, kg)];
      acc[0][0] = mfma16(a0h, b0, acc[0][0]);
      acc[0][1] = mfma16(a0h, b1, acc[0][1]);
      acc[1][0] = mfma16(a1h, b0, acc[1][0]);
      acc[1][1] = mfma16(a1h, b1, acc[1][1]);
      if (AT == 2) {
        bf16x8 a0l = *(const bf16x8*)&lds[bf][1][TADDR(ra0, kg)];
        bf16x8 a1l = *(const bf16x8*)&lds[bf][1][TADDR(ra1, kg)];
        acc[0][0] = mfma16(a0l, b0, acc[0][0]);
        acc[0][1] = mfma16(a0l, b1, acc[0][1]);
        acc[1][0] = mfma16(a1l, b0, acc[1][0]);
        acc[1][1] = mfma16(a1l, b1, acc[1][1]);
      }
    }
    __syncthreads();
    bf ^= 1;
  }
#pragma unroll
  for (int ni = 0; ni < 2; ++ni) {
    const int col = colBase + wc * 32 + ni * 16 + l15;
#pragma unroll
    for (int mi = 0; mi < 2; ++mi) {
      float vpart = 0.f;
      int curb = -1;
#pragma unroll
      for (int r2 = 0; r2 < 4; ++r2) {
        const int row = rowBase + wr * 32 + mi * 16 + l4 * 4 + r2;
        if (row < BL) {
          if (MODE == 0) {
            Cf[(size_t)row * 1024 + col] = acc[mi][ni][r2] + bias0[col];
          } else {
            if (col < 1024) {
              float val = acc[mi][ni][r2] + bias0[col];
              bf16_t h, lo; split2(val, h, lo);
              Ch[(size_t)row * 1024 + col] = h;
              Cl[(size_t)row * 1024 + col] = lo;
            } else {
              const int vcol = col - 1024;
              const float val = acc[mi][ni][r2] + bias1[vcol];
              Cf[(size_t)row * 1024 + vcol] = val;
              const int b = row / L;
              if (b != curb) {
                if (curb >= 0)
                  atomicAdd(&vsum[(size_t)(curb * 8) * DH + vcol], vpart);
                curb = b; vpart = 0.f;
              }
              vpart += val;
            }
          }
        }
      }
      if (MODE == 1 && curb >= 0)
        atomicAdd(&vsum[(size_t)(curb * 8) * DH + (col - 1024)], vpart);
    }
  }
}

// ---------- qf3: fused dd-GEMM (in-register) + rf + maxes + exp + 5 reductions ----------
// Block = 512 threads / 8 waves; 32 q-rows x 640 cols; 5 dbuf chunks of 128 B-rows.
// Wave w owns cols {c*128 + w*16 + l15}. Writes fd[r][0..4]. Grid 202.
__global__ __launch_bounds__(512) void qf3_kernel(const bf16_t* __restrict__ qh,
                                                  const bf16_t* __restrict__ ql,
                                                  const bf16_t* __restrict__ rh,
                                                  const bf16_t* __restrict__ rl,
                                                  const bf16_t* __restrict__ ph,
                                                  const float* __restrict__ rpe,
                                                  float* __restrict__ fd) {
  const int tid = threadIdx.x;
  __shared__ bf16_t Ahl[2][48 * 128];   // [h,l]; rows 0..31 q, 32..47 rf(pad)
  __shared__ bf16_t Bch[2][128 * 128];  // [dbuf] chunk of ph (128 rows)
  __shared__ float rfs[5][MFP];
  __shared__ float diag[32];
  __shared__ float diag5v[8];
  __shared__ float mxs[8][32];
  __shared__ float mxAll[32];
  __shared__ float mxrf[8];
  __shared__ float sred[8][32][5];
  const int w = tid >> 6, lane = tid & 63;
  const int l15 = lane & 15, l4 = lane >> 4;
  const int r0 = blockIdx.x * 32;
  const int r4 = lane >> 4;        // 0..3 (row within 4-row group)
  const int cg = lane & 15;        // dest col16
  // ---- A stage (once): w0/w1 qh halves, w2/w3 ql halves, w4 rh, w5 rl ----
  // each gload_lds16 writes 512 ELEMENTS (1024 B) -> per-instr dst stride is j*512
  if (w < 6) {
    const bf16_t* srcA = (w < 2) ? qh : (w < 4) ? ql : (w == 4) ? rh : rl;
    const int arow0 = (w < 4) ? (r0 + (w & 1) * 16) : 0;
    bf16_t* dstA = &Ahl[(w < 4) ? (w >> 1) : (w - 4)][((w < 4) ? (w & 1) * 16 : 32) * 128];
    const bf16_t* peA = srcA + (size_t)(arow0 + r4) * DH + ((cg ^ r4) << 3);
    const bf16_t* poA = srcA + (size_t)(arow0 + r4) * DH + ((cg ^ r4 ^ 4) << 3);
#pragma unroll
    for (int j = 0; j < 4; ++j)
      gload_lds16(((j & 1) ? poA : peA) + (size_t)(4 * j) * DH, dstA + j * 512);
  }
  // ---- B chunk stage: wave w stages rows w*16..w*16+15 of the 128-row chunk ----
  const bf16_t* peB = ph + (size_t)(w * 16 + r4) * DH + ((cg ^ r4) << 3);
  const bf16_t* poB = ph + (size_t)(w * 16 + r4) * DH + ((cg ^ r4 ^ 4) << 3);
  auto STAGE_B = [&](int buf, int c) {
    const size_t coff = (size_t)c * 128 * DH;
#pragma unroll
    for (int j = 0; j < 4; ++j)
      gload_lds16(((j & 1) ? poB : peB) + coff + (size_t)(4 * j) * DH,
                  &Bch[buf][(w * 16 + j * 4) * 128]);
  };
  // ---- diag (q rows, first 256 threads) / diag5v ----
  if (tid < 256) {
    const int row = tid >> 3, ch = tid & 7;
    const size_t base = (size_t)(r0 + row) * DH + ch * 16;
    float s = 0.f;
#pragma unroll
    for (int t = 0; t < 2; ++t) {
      bf16x8 vh = *(const bf16x8*)(qh + base + t * 8);
      bf16x8 vl = *(const bf16x8*)(ql + base + t * 8);
#pragma unroll
      for (int e = 0; e < 8; ++e) {
        float f = (float)vh[e] + (float)vl[e];
        s += f * f;
      }
    }
    s += __shfl_xor(s, 1, 64); s += __shfl_xor(s, 2, 64); s += __shfl_xor(s, 4, 64);
    if (ch == 0) diag[row] = (0.5f * DN2) * s;
  }
  if (tid < 40) {
    const int row = tid >> 3, ch = tid & 7;
    float s = 0.f;
#pragma unroll
    for (int e = 0; e < 16; ++e) { float f = rpe[row * DH + ch * 16 + e]; s += f * f; }
    s += __shfl_xor(s, 1, 64); s += __shfl_xor(s, 2, 64); s += __shfl_xor(s, 4, 64);
    if (ch == 0) diag5v[row] = (0.5f * DN2) * s;
  }
  // ---- main loop: 5 chunks x 4 k-steps ----
  auto TADDR = [](int row, int kg) { return row * 128 + (((kg) ^ (row & 7)) << 3); };
  f32x4 acc[2][5] = {};
  f32x4 accr[5] = {};
  STAGE_B(0, 0);
  __syncthreads();
  int buf = 0;
#pragma unroll
  for (int c = 0; c < 5; ++c) {
    if (c + 1 < 5) STAGE_B(buf ^ 1, c + 1);
#pragma unroll
    for (int ks = 0; ks < 4; ++ks) {
      const int kg = ks * 4 + l4;
      bf16x8 a0h = *(const bf16x8*)&Ahl[0][TADDR(l15, kg)];
      bf16x8 a0l = *(const bf16x8*)&Ahl[1][TADDR(l15, kg)];
      bf16x8 a1h = *(const bf16x8*)&Ahl[0][TADDR(16 + l15, kg)];
      bf16x8 a1l = *(const bf16x8*)&Ahl[1][TADDR(16 + l15, kg)];
      bf16x8 arh = *(const bf16x8*)&Ahl[0][TADDR(32 + l15, kg)];
      bf16x8 arl = *(const bf16x8*)&Ahl[1][TADDR(32 + l15, kg)];
      bf16x8 bb  = *(const bf16x8*)&Bch[buf][TADDR(w * 16 + l15, kg)];
      acc[0][c] = mfma16(a0h, bb, acc[0][c]);
      acc[0][c] = mfma16(a0l, bb, acc[0][c]);
      acc[1][c] = mfma16(a1h, bb, acc[1][c]);
      acc[1][c] = mfma16(a1l, bb, acc[1][c]);
      accr[c]   = mfma16(arh, bb, accr[c]);
      accr[c]   = mfma16(arl, bb, accr[c]);
    }
    __syncthreads();
    buf ^= 1;
  }
  // ---- q per-row max ----
  float pm[2][4];
#pragma unroll
  for (int mi = 0; mi < 2; ++mi)
#pragma unroll
    for (int r2 = 0; r2 < 4; ++r2) {
      float m = -3.4e38f;
#pragma unroll
      for (int c = 0; c < 5; ++c) {
        const int col = c * 128 + w * 16 + l15;
        float vv = (col < MF) ? acc[mi][c][r2] : -3.4e38f;
        m = fmaxf(m, vv);
      }
      pm[mi][r2] = m;
    }
#pragma unroll
  for (int mask = 1; mask <= 8; mask <<= 1)
#pragma unroll
    for (int mi = 0; mi < 2; ++mi)
#pragma unroll
      for (int r2 = 0; r2 < 4; ++r2)
        pm[mi][r2] = fmaxf(pm[mi][r2], __shfl_xor(pm[mi][r2], mask, 64));
  if (l15 == 0) {
#pragma unroll
    for (int mi = 0; mi < 2; ++mi)
#pragma unroll
      for (int r2 = 0; r2 < 4; ++r2)
        mxs[w][mi * 16 + l4 * 4 + r2] = pm[mi][r2];
  }
  // ---- rf global max ----
  {
    float m = -3.4e38f;
#pragma unroll
    for (int c = 0; c < 5; ++c) {
      const int col = c * 128 + w * 16 + l15;
#pragma unroll
      for (int r2 = 0; r2 < 4; ++r2) {
        const int row5 = l4 * 4 + r2;
        if (row5 < 5 && col < MF) m = fmaxf(m, accr[c][r2]);
      }
    }
#pragma unroll
    for (int mask = 1; mask <= 32; mask <<= 1) m = fmaxf(m, __shfl_xor(m, mask, 64));
    if (lane == 0) mxrf[w] = m;
  }
  __syncthreads();
  // ---- rf exp -> rfs ----
  {
    float mxR = mxrf[0];
#pragma unroll
    for (int i = 1; i < 8; ++i) mxR = fmaxf(mxR, mxrf[i]);
#pragma unroll
    for (int c = 0; c < 5; ++c) {
      const int col = c * 128 + w * 16 + l15;
#pragma unroll
      for (int r2 = 0; r2 < 4; ++r2) {
        const int row5 = l4 * 4 + r2;
        if (row5 < 5) {
          float val = (col < MF)
              ? RATIO * (__expf(accr[c][r2] - diag5v[row5] - mxR) + EPS) : 0.f;
          rfs[row5][col] = val;
        }
      }
    }
  }
  if (tid < 32) {
    float m = mxs[0][tid];
#pragma unroll
    for (int i = 1; i < 8; ++i) m = fmaxf(m, mxs[i][tid]);
    mxAll[tid] = m;
  }
  __syncthreads();
  for (int i = tid; i < 4 * MFP; i += 512) rfs[i / MFP][i % MFP] -= rfs[4][i % MFP];
  __syncthreads();
  // ---- qf exp + 5 weighted sums ----
  float s[2][4][5] = {};
#pragma unroll
  for (int mi = 0; mi < 2; ++mi)
#pragma unroll
    for (int r2 = 0; r2 < 4; ++r2) {
      const int row = mi * 16 + l4 * 4 + r2;
      const float sub = diag[row] + mxAll[row];
#pragma unroll
      for (int c = 0; c < 5; ++c) {
        const int col = c * 128 + w * 16 + l15;
        const float qfv = RATIO * (__expf(acc[mi][c][r2] - sub) + EPS);
#pragma unroll
        for (int cc = 0; cc < 5; ++cc) s[mi][r2][cc] += qfv * rfs[cc][col];
      }
    }
#pragma unroll
  for (int mask = 1; mask <= 8; mask <<= 1)
#pragma unroll
    for (int mi = 0; mi < 2; ++mi)
#pragma unroll
      for (int r2 = 0; r2 < 4; ++r2)
#pragma unroll
        for (int cc = 0; cc < 5; ++cc)
          s[mi][r2][cc] += __shfl_xor(s[mi][r2][cc], mask, 64);
  if (l15 == 0) {
#pragma unroll
    for (int mi = 0; mi < 2; ++mi)
#pragma unroll
      for (int r2 = 0; r2 < 4; ++r2)
#pragma unroll
        for (int cc = 0; cc < 5; ++cc)
          sred[w][mi * 16 + l4 * 4 + r2][cc] = s[mi][r2][cc];
  }
  __syncthreads();
  if (tid < 160) {
    const int row = tid / 5, cc = tid % 5;
    float acc5 = sred[0][row][cc];
#pragma unroll
    for (int i = 1; i < 8; ++i) acc5 += sred[i][row][cc];
    fd[(size_t)(r0 + row) * 8 + cc] = acc5;
  }
}

// ---------- gather + normalize + bf16 attn (hi only) ----------
__global__ __launch_bounds__(256) void out_kernel(const float* __restrict__ fd,
                                                  const float* __restrict__ v,
                                                  const float* __restrict__ vsum,
                                                  bf16_t* __restrict__ attnh) {
  const int tid = threadIdx.x;
  const int sub = tid >> 7, d = tid & 127;
  const int bh = blockIdx.y, b = bh >> 3, h = bh & 7;
  const int l = blockIdx.x * 2 + sub;
  if (l >= L) return;
  const size_t r = (size_t)(b * L + l) * H + h;
  const float q0 = fd[r * 8 + 0], q1 = fd[r * 8 + 1], q2 = fd[r * 8 + 2],
              q3 = fd[r * 8 + 3], sM = fd[r * 8 + 4];
  float o = sM * vsum[(size_t)bh * DH + d];
  float c0 = 0, c1 = 0, c2 = 0, c3 = 0;
  const int xo = (l < 100) ? (l % 10) : 0;
  const int yo = (l < 100) ? (l / 10) : 10;
#pragma unroll
  for (int k = 0; k < 49; ++k) {
    const int dx = (k % 7) - 3, dy = (k / 7) - 3;
    const int xp = xo + dx, yp = yo + dy;
    const int df = (dx < 0 ? -dx : dx) + (dy < 0 ? -dy : dy);
    if (xp >= 0 && xp < 10 && yp >= 0 && yp < 10 && df < 4) {
      float qq;
      if (df == 0)      { c0 += 1.f; qq = q0; }
      else if (df == 1) { c1 += 1.f; qq = q1; }
      else if (df == 2) { c2 += 1.f; qq = q2; }
      else              { c3 += 1.f; qq = q3; }
      const int pos = l + dx + 10 * dy;
      o += qq * v[(size_t)(b * L + pos) * DIM + h * DH + d];
    }
  }
  const float D = c0 * q0 + c1 * q1 + c2 * q2 + c3 * q3 + (float)L * sM;
  attnh[(size_t)(b * L + l) * DIM + h * DH + d] = (bf16_t)(o / D);
}

}  // namespace

extern "C" void kernel_launch(void* const* d_in, const int* in_sizes, int n_in,
                              void* d_out, int out_size, void* d_ws, size_t ws_size,
                              hipStream_t stream) {
  const float* x    = (const float*)d_in[0];
  const float* Wq   = (const float*)d_in[1];
  const float* bq   = (const float*)d_in[2];
  const float* Wv   = (const float*)d_in[3];
  const float* bv   = (const float*)d_in[4];
  const float* rpe  = (const float*)d_in[5];
  const float* proj = (const float*)d_in[6];
  const float* Wo   = (const float*)d_in[7];
  const float* bo   = (const float*)d_in[8];

  char* p = (char*)d_ws;
  auto alloc = [&](size_t bytes) { char* r = p; p += (bytes + 255) & ~255ull; return r; };
  bf16_t* xh  = (bf16_t*)alloc((size_t)BLP * DIM * 2);
  bf16_t* Wh  = (bf16_t*)alloc((size_t)2 * DIM * DIM * 2);  // Wq rows 0..1023, Wv rows 1024..2047
  bf16_t* Woh = (bf16_t*)alloc((size_t)DIM * DIM * 2);
  bf16_t* ph  = (bf16_t*)alloc((size_t)MFP * DH * 2);
  bf16_t* rh  = (bf16_t*)alloc((size_t)64 * DH * 2);
  bf16_t* rl  = (bf16_t*)alloc((size_t)64 * DH * 2);
  bf16_t* qh  = (bf16_t*)alloc((size_t)BLP * DIM * 2);   // q, later attn
  bf16_t* ql  = (bf16_t*)alloc((size_t)BLP * DIM * 2);
  float*  v   = (float*)alloc((size_t)BL * DIM * 4);
  float*  fd  = (float*)alloc((size_t)RR * 8 * 4);
  float*  vsm = (float*)alloc((size_t)BH * DH * 4);

  split_all<<<(NTOT + 255) / 256, 256, 0, stream>>>(x, proj, rpe, Wq, Wv, Wo,
                                                    xh, ph, rh, rl,
                                                    Wh, Woh, qh, ql, vsm);
  // fused q+v projection: N=2048, 1-term A, BK=64 (416 blocks) + vsum atomics
  gemm64<1, 1><<<dim3(32, 13), 256, 0, stream>>>(xh, nullptr, Wh, bq, bv,
                                                 v, qh, ql, vsm);
  // fused dd + feature reductions (202 blocks x 512 threads)
  qf3_kernel<<<202, 512, 0, stream>>>(qh, ql, rh, rl, ph, rpe, fd);
  out_kernel<<<dim3((L + 1) / 2, BH), 256, 0, stream>>>(fd, v, vsm, qh);
  // output projection: 1-term A, BK=64 (208 blocks)
  gemm64<0, 1><<<dim3(16, 13), 256, 0, stream>>>(qh, nullptr, Woh, bo, nullptr,
                                                 (float*)d_out, nullptr, nullptr, nullptr);
}

// Round 15
// 68.532 us; speedup vs baseline: 2.0156x; 1.0442x over previous
//
#include <hip/hip_runtime.h>
#include <math.h>

namespace {

typedef __bf16 bf16_t;
typedef bf16_t bf16x8 __attribute__((ext_vector_type(8)));
typedef bf16_t bf16x4 __attribute__((ext_vector_type(4)));
typedef float f32x4 __attribute__((ext_vector_type(4)));

constexpr int B = 8, L = 101, DIM = 1024, H = 8, DH = 128, MF = 621, MFP = 640;
constexpr int BL = B * L;    // 808
constexpr int BLP = 832;     // padded rows for GEMM A
constexpr int BH = B * H;    // 64
constexpr int RR = BL * H;   // 6464

constexpr float DN    = 0.29730177875068026f;   // 128^-0.25
constexpr float DN2   = 0.08838834764831845f;   // 128^-0.5
constexpr float RATIO = 0.04012861672f;         // 621^-0.5
constexpr float EPS   = 1e-4f;

// split_all segment sizes (bf16x4 / float4 units)
constexpr int NX = BL * DIM / 4;    // 206848 (x -> xh only)
constexpr int NP = MFP * 32;        // 20480  (proj -> ph only)
constexpr int NR = 64 * DH / 4;     // 2048   (rpe, padded to 64 rows, split)
constexpr int NW = DIM * DIM / 4;   // 262144
constexpr int NZ = 3 * (BLP - BL) * DIM / 4;  // 18432 pad-zero units (xh,qh,ql)
constexpr int NV = BH * DH / 4;     // 2048 (vsum zero)
constexpr int NTOT = NX + NP + NR + 3 * NW + NZ + NV;

__device__ __forceinline__ f32x4 mfma16(bf16x8 a, bf16x8 b, f32x4 c) {
  return __builtin_amdgcn_mfma_f32_16x16x32_bf16(a, b, c, 0, 0, 0);
}

__device__ __forceinline__ void split2(float f, bf16_t& h, bf16_t& l) {
  h = (bf16_t)f;
  l = (bf16_t)(f - (float)h);
}

__device__ __forceinline__ void gload_lds16(const bf16_t* g, bf16_t* l) {
  __builtin_amdgcn_global_load_lds(
      (const __attribute__((address_space(1))) void*)g,
      (__attribute__((address_space(3))) void*)l, 16, 0, 0);
}

// ---------- one-shot convert/split of everything (+ vsum zero) ----------
__global__ __launch_bounds__(256) void split_all(const float* __restrict__ x,
                                                 const float* __restrict__ proj,
                                                 const float* __restrict__ rpe,
                                                 const float* __restrict__ Wq,
                                                 const float* __restrict__ Wv,
                                                 const float* __restrict__ Wo,
                                                 bf16_t* __restrict__ xh,
                                                 bf16_t* __restrict__ ph,
                                                 bf16_t* __restrict__ rh, bf16_t* __restrict__ rl,
                                                 bf16_t* __restrict__ Wh,
                                                 bf16_t* __restrict__ Woh,
                                                 bf16_t* __restrict__ qh, bf16_t* __restrict__ ql,
                                                 float* __restrict__ vsum) {
  const int u = blockIdx.x * 256 + threadIdx.x;
  if (u >= NTOT) return;
  auto emit2 = [](const float* s4, float sc, bf16_t* dh, bf16_t* dl, size_t off) {
    float4 f = *(const float4*)s4;
    bf16x4 hv, lv; bf16_t h, l;
    split2(f.x * sc, h, l); hv[0] = h; lv[0] = l;
    split2(f.y * sc, h, l); hv[1] = h; lv[1] = l;
    split2(f.z * sc, h, l); hv[2] = h; lv[2] = l;
    split2(f.w * sc, h, l); hv[3] = h; lv[3] = l;
    *(bf16x4*)(dh + off) = hv;
    *(bf16x4*)(dl + off) = lv;
  };
  auto emit1 = [](const float* s4, float sc, bf16_t* dh, size_t off) {
    float4 f = *(const float4*)s4;
    bf16x4 hv;
    hv[0] = (bf16_t)(f.x * sc); hv[1] = (bf16_t)(f.y * sc);
    hv[2] = (bf16_t)(f.z * sc); hv[3] = (bf16_t)(f.w * sc);
    *(bf16x4*)(dh + off) = hv;
  };
  int t = u;
  if (t < NX) { emit1(x + (size_t)t * 4, 1.f, xh, (size_t)t * 4); return; }
  t -= NX;
  if (t < NP) {
    if ((t >> 5) < MF) emit1(proj + (size_t)t * 4, DN, ph, (size_t)t * 4);
    else { bf16x4 z = {}; *(bf16x4*)(ph + (size_t)t * 4) = z; }
    return;
  }
  t -= NP;
  if (t < NR) {
    if (t < 5 * DH / 4) emit2(rpe + (size_t)t * 4, 1.f, rh, rl, (size_t)t * 4);
    else { bf16x4 z = {}; *(bf16x4*)(rh + (size_t)t * 4) = z; *(bf16x4*)(rl + (size_t)t * 4) = z; }
    return;
  }
  t -= NR;
  if (t < NW) { emit1(Wq + (size_t)t * 4, 1.f, Wh, (size_t)t * 4); return; }
  t -= NW;
  if (t < NW) { emit1(Wv + (size_t)t * 4, 1.f, Wh, (size_t)(t + NW) * 4); return; }
  t -= NW;
  if (t < NW) { emit1(Wo + (size_t)t * 4, 1.f, Woh, (size_t)t * 4); return; }
  t -= NW;
  if (t < NZ) {  // zero pads rows 808..831 of xh,qh,ql
    const int buf = t / 6144, o = t % 6144;
    bf16_t* dst = (buf == 0) ? xh : (buf == 1) ? qh : ql;
    bf16x4 z = {};
    *(bf16x4*)(dst + (size_t)BL * DIM + (size_t)o * 4) = z;
    return;
  }
  t -= NZ;
  ((float4*)vsum)[t] = make_float4(0.f, 0.f, 0.f, 0.f);
}

// ---------- BK=128 LDS-staged 1-term MFMA GEMM, block tile 64x64, 4 waves 32x32 ----------
// C = A @ B^T, A/B plain bf16. LDS rows are 128 cols; qf3-proven swizzle:
// read slot = kg ^ (row&7); staged with pe/po pointers (cg^r4 / cg^r4^4).
// MODE 0: f32 out + bias0 (o-proj). MODE 1: qv — q bf16-split / v f32 + vsum atomics.
template<int MODE>
__global__ __launch_bounds__(256) void gemm128(const bf16_t* __restrict__ Ah,
                                               const bf16_t* __restrict__ Bh,
                                               const float* __restrict__ bias0,
                                               const float* __restrict__ bias1,
                                               float* __restrict__ Cf,
                                               bf16_t* __restrict__ Ch,
                                               bf16_t* __restrict__ Cl,
                                               float* __restrict__ vsum) {
  constexpr int K = 1024, BK = 128, NK = K / BK;  // 8 steps
  __shared__ bf16_t lds[2][2][64 * 128];          // [dbuf][A,B]
  const int tid = threadIdx.x;
  const int w = tid >> 6, lane = tid & 63;
  const int wr = w >> 1, wc = w & 1;
  const int l15 = lane & 15, l4 = lane >> 4;
  const int rowBase = blockIdx.y * 64, colBase = blockIdx.x * 64;
  // staging (qf3 pattern): 64 lanes = 4 rows x 16 col16-slots per instr, 8 instrs = 32 rows
  const int r4 = lane >> 4;        // 0..3 row-in-group
  const int cg = lane & 15;        // dest col16 slot
  const bf16_t* src = (w < 2) ? Ah : Bh;
  const int grow0 = ((w < 2) ? rowBase : colBase) + (w & 1) * 32;
  const int ti = (w < 2) ? 0 : 1;
  const int dst0 = (w & 1) * 32 * 128;
  const bf16_t* pe = src + (size_t)(grow0 + r4) * K + ((cg ^ r4) << 3);
  const bf16_t* po = src + (size_t)(grow0 + r4) * K + ((cg ^ r4 ^ 4) << 3);
  auto STAGE = [&](int bf, int k0) {
#pragma unroll
    for (int j = 0; j < 8; ++j)
      gload_lds16(((j & 1) ? po : pe) + (size_t)(4 * j) * K + k0,
                  &lds[bf][ti][dst0 + j * 512]);
  };
  const int ra0 = wr * 32 + l15, ra1 = ra0 + 16;
  const int rb0 = wc * 32 + l15, rb1 = rb0 + 16;
  auto TADDR = [](int row, int kg) { return row * 128 + (((kg) ^ (row & 7)) << 3); };
  f32x4 acc[2][2] = {};
  STAGE(0, 0);
  __syncthreads();
  int bf = 0;
  for (int ks = 0; ks < NK; ++ks) {
    if (ks + 1 < NK) STAGE(bf ^ 1, (ks + 1) * BK);
#pragma unroll
    for (int subk = 0; subk < 4; ++subk) {
      const int kg = subk * 4 + l4;
      bf16x8 a0 = *(const bf16x8*)&lds[bf][0][TADDR(ra0, kg)];
      bf16x8 a1 = *(const bf16x8*)&lds[bf][0][TADDR(ra1, kg)];
      bf16x8 b0 = *(const bf16x8*)&lds[bf][1][TADDR(rb0, kg)];
      bf16x8 b1 = *(const bf16x8*)&lds[bf][1][TADDR(rb1, kg)];
      acc[0][0] = mfma16(a0, b0, acc[0][0]);
      acc[0][1] = mfma16(a0, b1, acc[0][1]);
      acc[1][0] = mfma16(a1, b0, acc[1][0]);
      acc[1][1] = mfma16(a1, b1, acc[1][1]);
    }
    __syncthreads();
    bf ^= 1;
  }
#pragma unroll
  for (int ni = 0; ni < 2; ++ni) {
    const int col = colBase + wc * 32 + ni * 16 + l15;
#pragma unroll
    for (int mi = 0; mi < 2; ++mi) {
      float vpart = 0.f;
      int curb = -1;
#pragma unroll
      for (int r2 = 0; r2 < 4; ++r2) {
        const int row = rowBase + wr * 32 + mi * 16 + l4 * 4 + r2;
        if (row < BL) {
          if (MODE == 0) {
            Cf[(size_t)row * 1024 + col] = acc[mi][ni][r2] + bias0[col];
          } else {
            if (col < 1024) {
              float val = acc[mi][ni][r2] + bias0[col];
              bf16_t h, lo; split2(val, h, lo);
              Ch[(size_t)row * 1024 + col] = h;
              Cl[(size_t)row * 1024 + col] = lo;
            } else {
              const int vcol = col - 1024;
              const float val = acc[mi][ni][r2] + bias1[vcol];
              Cf[(size_t)row * 1024 + vcol] = val;
              const int b = row / L;
              if (b != curb) {
                if (curb >= 0)
                  atomicAdd(&vsum[(size_t)(curb * 8) * DH + vcol], vpart);
                curb = b; vpart = 0.f;
              }
              vpart += val;
            }
          }
        }
      }
      if (MODE == 1 && curb >= 0)
        atomicAdd(&vsum[(size_t)(curb * 8) * DH + (col - 1024)], vpart);
    }
  }
}

// ---------- qf3: fused dd-GEMM (in-register) + rf + maxes + exp + 5 reductions ----------
// Block = 512 threads / 8 waves; 32 q-rows x 640 cols; 5 dbuf chunks of 128 B-rows.
__global__ __launch_bounds__(512) void qf3_kernel(const bf16_t* __restrict__ qh,
                                                  const bf16_t* __restrict__ ql,
                                                  const bf16_t* __restrict__ rh,
                                                  const bf16_t* __restrict__ rl,
                                                  const bf16_t* __restrict__ ph,
                                                  const float* __restrict__ rpe,
                                                  float* __restrict__ fd) {
  const int tid = threadIdx.x;
  __shared__ bf16_t Ahl[2][48 * 128];   // [h,l]; rows 0..31 q, 32..47 rf(pad)
  __shared__ bf16_t Bch[2][128 * 128];  // [dbuf] chunk of ph (128 rows)
  __shared__ float rfs[5][MFP];
  __shared__ float diag[32];
  __shared__ float diag5v[8];
  __shared__ float mxs[8][32];
  __shared__ float mxAll[32];
  __shared__ float mxrf[8];
  __shared__ float sred[8][32][5];
  const int w = tid >> 6, lane = tid & 63;
  const int l15 = lane & 15, l4 = lane >> 4;
  const int r0 = blockIdx.x * 32;
  const int r4 = lane >> 4;        // 0..3 (row within 4-row group)
  const int cg = lane & 15;        // dest col16
  // ---- A stage (once): w0/w1 qh halves, w2/w3 ql halves, w4 rh, w5 rl ----
  // each gload_lds16 writes 512 ELEMENTS (1024 B) -> per-instr dst stride is j*512
  if (w < 6) {
    const bf16_t* srcA = (w < 2) ? qh : (w < 4) ? ql : (w == 4) ? rh : rl;
    const int arow0 = (w < 4) ? (r0 + (w & 1) * 16) : 0;
    bf16_t* dstA = &Ahl[(w < 4) ? (w >> 1) : (w - 4)][((w < 4) ? (w & 1) * 16 : 32) * 128];
    const bf16_t* peA = srcA + (size_t)(arow0 + r4) * DH + ((cg ^ r4) << 3);
    const bf16_t* poA = srcA + (size_t)(arow0 + r4) * DH + ((cg ^ r4 ^ 4) << 3);
#pragma unroll
    for (int j = 0; j < 4; ++j)
      gload_lds16(((j & 1) ? poA : peA) + (size_t)(4 * j) * DH, dstA + j * 512);
  }
  // ---- B chunk stage ----
  const bf16_t* peB = ph + (size_t)(w * 16 + r4) * DH + ((cg ^ r4) << 3);
  const bf16_t* poB = ph + (size_t)(w * 16 + r4) * DH + ((cg ^ r4 ^ 4) << 3);
  auto STAGE_B = [&](int buf, int c) {
    const size_t coff = (size_t)c * 128 * DH;
#pragma unroll
    for (int j = 0; j < 4; ++j)
      gload_lds16(((j & 1) ? poB : peB) + coff + (size_t)(4 * j) * DH,
                  &Bch[buf][(w * 16 + j * 4) * 128]);
  };
  // ---- diag (q rows, first 256 threads) / diag5v ----
  if (tid < 256) {
    const int row = tid >> 3, ch = tid & 7;
    const size_t base = (size_t)(r0 + row) * DH + ch * 16;
    float s = 0.f;
#pragma unroll
    for (int t = 0; t < 2; ++t) {
      bf16x8 vh = *(const bf16x8*)(qh + base + t * 8);
      bf16x8 vl = *(const bf16x8*)(ql + base + t * 8);
#pragma unroll
      for (int e = 0; e < 8; ++e) {
        float f = (float)vh[e] + (float)vl[e];
        s += f * f;
      }
    }
    s += __shfl_xor(s, 1, 64); s += __shfl_xor(s, 2, 64); s += __shfl_xor(s, 4, 64);
    if (ch == 0) diag[row] = (0.5f * DN2) * s;
  }
  if (tid < 40) {
    const int row = tid >> 3, ch = tid & 7;
    float s = 0.f;
#pragma unroll
    for (int e = 0; e < 16; ++e) { float f = rpe[row * DH + ch * 16 + e]; s += f * f; }
    s += __shfl_xor(s, 1, 64); s += __shfl_xor(s, 2, 64); s += __shfl_xor(s, 4, 64);
    if (ch == 0) diag5v[row] = (0.5f * DN2) * s;
  }
  // ---- main loop: 5 chunks x 4 k-steps ----
  auto TADDR = [](int row, int kg) { return row * 128 + (((kg) ^ (row & 7)) << 3); };
  f32x4 acc[2][5] = {};
  f32x4 accr[5] = {};
  STAGE_B(0, 0);
  __syncthreads();
  int buf = 0;
#pragma unroll
  for (int c = 0; c < 5; ++c) {
    if (c + 1 < 5) STAGE_B(buf ^ 1, c + 1);
#pragma unroll
    for (int ks = 0; ks < 4; ++ks) {
      const int kg = ks * 4 + l4;
      bf16x8 a0h = *(const bf16x8*)&Ahl[0][TADDR(l15, kg)];
      bf16x8 a0l = *(const bf16x8*)&Ahl[1][TADDR(l15, kg)];
      bf16x8 a1h = *(const bf16x8*)&Ahl[0][TADDR(16 + l15, kg)];
      bf16x8 a1l = *(const bf16x8*)&Ahl[1][TADDR(16 + l15, kg)];
      bf16x8 arh = *(const bf16x8*)&Ahl[0][TADDR(32 + l15, kg)];
      bf16x8 arl = *(const bf16x8*)&Ahl[1][TADDR(32 + l15, kg)];
      bf16x8 bb  = *(const bf16x8*)&Bch[buf][TADDR(w * 16 + l15, kg)];
      acc[0][c] = mfma16(a0h, bb, acc[0][c]);
      acc[0][c] = mfma16(a0l, bb, acc[0][c]);
      acc[1][c] = mfma16(a1h, bb, acc[1][c]);
      acc[1][c] = mfma16(a1l, bb, acc[1][c]);
      accr[c]   = mfma16(arh, bb, accr[c]);
      accr[c]   = mfma16(arl, bb, accr[c]);
    }
    __syncthreads();
    buf ^= 1;
  }
  // ---- q per-row max ----
  float pm[2][4];
#pragma unroll
  for (int mi = 0; mi < 2; ++mi)
#pragma unroll
    for (int r2 = 0; r2 < 4; ++r2) {
      float m = -3.4e38f;
#pragma unroll
      for (int c = 0; c < 5; ++c) {
        const int col = c * 128 + w * 16 + l15;
        float vv = (col < MF) ? acc[mi][c][r2] : -3.4e38f;
        m = fmaxf(m, vv);
      }
      pm[mi][r2] = m;
    }
#pragma unroll
  for (int mask = 1; mask <= 8; mask <<= 1)
#pragma unroll
    for (int mi = 0; mi < 2; ++mi)
#pragma unroll
      for (int r2 = 0; r2 < 4; ++r2)
        pm[mi][r2] = fmaxf(pm[mi][r2], __shfl_xor(pm[mi][r2], mask, 64));
  if (l15 == 0) {
#pragma unroll
    for (int mi = 0; mi < 2; ++mi)
#pragma unroll
      for (int r2 = 0; r2 < 4; ++r2)
        mxs[w][mi * 16 + l4 * 4 + r2] = pm[mi][r2];
  }
  // ---- rf global max ----
  {
    float m = -3.4e38f;
#pragma unroll
    for (int c = 0; c < 5; ++c) {
      const int col = c * 128 + w * 16 + l15;
#pragma unroll
      for (int r2 = 0; r2 < 4; ++r2) {
        const int row5 = l4 * 4 + r2;
        if (row5 < 5 && col < MF) m = fmaxf(m, accr[c][r2]);
      }
    }
#pragma unroll
    for (int mask = 1; mask <= 32; mask <<= 1) m = fmaxf(m, __shfl_xor(m, mask, 64));
    if (lane == 0) mxrf[w] = m;
  }
  __syncthreads();
  // ---- rf exp -> rfs ----
  {
    float mxR = mxrf[0];
#pragma unroll
    for (int i = 1; i < 8; ++i) mxR = fmaxf(mxR, mxrf[i]);
#pragma unroll
    for (int c = 0; c < 5; ++c) {
      const int col = c * 128 + w * 16 + l15;
#pragma unroll
      for (int r2 = 0; r2 < 4; ++r2) {
        const int row5 = l4 * 4 + r2;
        if (row5 < 5) {
          float val = (col < MF)
              ? RATIO * (__expf(accr[c][r2] - diag5v[row5] - mxR) + EPS) : 0.f;
          rfs[row5][col] = val;
        }
      }
    }
  }
  if (tid < 32) {
    float m = mxs[0][tid];
#pragma unroll
    for (int i = 1; i < 8; ++i) m = fmaxf(m, mxs[i][tid]);
    mxAll[tid] = m;
  }
  __syncthreads();
  for (int i = tid; i < 4 * MFP; i += 512) rfs[i / MFP][i % MFP] -= rfs[4][i % MFP];
  __syncthreads();
  // ---- qf exp + 5 weighted sums ----
  float s[2][4][5] = {};
#pragma unroll
  for (int mi = 0; mi < 2; ++mi)
#pragma unroll
    for (int r2 = 0; r2 < 4; ++r2) {
      const int row = mi * 16 + l4 * 4 + r2;
      const float sub = diag[row] + mxAll[row];
#pragma unroll
      for (int c = 0; c < 5; ++c) {
        const int col = c * 128 + w * 16 + l15;
        const float qfv = RATIO * (__expf(acc[mi][c][r2] - sub) + EPS);
#pragma unroll
        for (int cc = 0; cc < 5; ++cc) s[mi][r2][cc] += qfv * rfs[cc][col];
      }
    }
#pragma unroll
  for (int mask = 1; mask <= 8; mask <<= 1)
#pragma unroll
    for (int mi = 0; mi < 2; ++mi)
#pragma unroll
      for (int r2 = 0; r2 < 4; ++r2)
#pragma unroll
        for (int cc = 0; cc < 5; ++cc)
          s[mi][r2][cc] += __shfl_xor(s[mi][r2][cc], mask, 64);
  if (l15 == 0) {
#pragma unroll
    for (int mi = 0; mi < 2; ++mi)
#pragma unroll
      for (int r2 = 0; r2 < 4; ++r2)
#pragma unroll
        for (int cc = 0; cc < 5; ++cc)
          sred[w][mi * 16 + l4 * 4 + r2][cc] = s[mi][r2][cc];
  }
  __syncthreads();
  if (tid < 160) {
    const int row = tid / 5, cc = tid % 5;
    float acc5 = sred[0][row][cc];
#pragma unroll
    for (int i = 1; i < 8; ++i) acc5 += sred[i][row][cc];
    fd[(size_t)(r0 + row) * 8 + cc] = acc5;
  }
}

// ---------- gather + normalize + bf16 attn (hi only) ----------
__global__ __launch_bounds__(256) void out_kernel(const float* __restrict__ fd,
                                                  const float* __restrict__ v,
                                                  const float* __restrict__ vsum,
                                                  bf16_t* __restrict__ attnh) {
  const int tid = threadIdx.x;
  const int sub = tid >> 7, d = tid & 127;
  const int bh = blockIdx.y, b = bh >> 3, h = bh & 7;
  const int l = blockIdx.x * 2 + sub;
  if (l >= L) return;
  const size_t r = (size_t)(b * L + l) * H + h;
  const float q0 = fd[r * 8 + 0], q1 = fd[r * 8 + 1], q2 = fd[r * 8 + 2],
              q3 = fd[r * 8 + 3], sM = fd[r * 8 + 4];
  float o = sM * vsum[(size_t)bh * DH + d];
  float c0 = 0, c1 = 0, c2 = 0, c3 = 0;
  const int xo = (l < 100) ? (l % 10) : 0;
  const int yo = (l < 100) ? (l / 10) : 10;
#pragma unroll
  for (int k = 0; k < 49; ++k) {
    const int dx = (k % 7) - 3, dy = (k / 7) - 3;
    const int xp = xo + dx, yp = yo + dy;
    const int df = (dx < 0 ? -dx : dx) + (dy < 0 ? -dy : dy);
    if (xp >= 0 && xp < 10 && yp >= 0 && yp < 10 && df < 4) {
      float qq;
      if (df == 0)      { c0 += 1.f; qq = q0; }
      else if (df == 1) { c1 += 1.f; qq = q1; }
      else if (df == 2) { c2 += 1.f; qq = q2; }
      else              { c3 += 1.f; qq = q3; }
      const int pos = l + dx + 10 * dy;
      o += qq * v[(size_t)(b * L + pos) * DIM + h * DH + d];
    }
  }
  const float D = c0 * q0 + c1 * q1 + c2 * q2 + c3 * q3 + (float)L * sM;
  attnh[(size_t)(b * L + l) * DIM + h * DH + d] = (bf16_t)(o / D);
}

}  // namespace

extern "C" void kernel_launch(void* const* d_in, const int* in_sizes, int n_in,
                              void* d_out, int out_size, void* d_ws, size_t ws_size,
                              hipStream_t stream) {
  const float* x    = (const float*)d_in[0];
  const float* Wq   = (const float*)d_in[1];
  const float* bq   = (const float*)d_in[2];
  const float* Wv   = (const float*)d_in[3];
  const float* bv   = (const float*)d_in[4];
  const float* rpe  = (const float*)d_in[5];
  const float* proj = (const float*)d_in[6];
  const float* Wo   = (const float*)d_in[7];
  const float* bo   = (const float*)d_in[8];

  char* p = (char*)d_ws;
  auto alloc = [&](size_t bytes) { char* r = p; p += (bytes + 255) & ~255ull; return r; };
  bf16_t* xh  = (bf16_t*)alloc((size_t)BLP * DIM * 2);
  bf16_t* Wh  = (bf16_t*)alloc((size_t)2 * DIM * DIM * 2);  // Wq rows 0..1023, Wv rows 1024..2047
  bf16_t* Woh = (bf16_t*)alloc((size_t)DIM * DIM * 2);
  bf16_t* ph  = (bf16_t*)alloc((size_t)MFP * DH * 2);
  bf16_t* rh  = (bf16_t*)alloc((size_t)64 * DH * 2);
  bf16_t* rl  = (bf16_t*)alloc((size_t)64 * DH * 2);
  bf16_t* qh  = (bf16_t*)alloc((size_t)BLP * DIM * 2);   // q, later attn
  bf16_t* ql  = (bf16_t*)alloc((size_t)BLP * DIM * 2);
  float*  v   = (float*)alloc((size_t)BL * DIM * 4);
  float*  fd  = (float*)alloc((size_t)RR * 8 * 4);
  float*  vsm = (float*)alloc((size_t)BH * DH * 4);

  split_all<<<(NTOT + 255) / 256, 256, 0, stream>>>(x, proj, rpe, Wq, Wv, Wo,
                                                    xh, ph, rh, rl,
                                                    Wh, Woh, qh, ql, vsm);
  // fused q+v projection: N=2048, 1-term, BK=128 (416 blocks) + vsum atomics
  gemm128<1><<<dim3(32, 13), 256, 0, stream>>>(xh, Wh, bq, bv, v, qh, ql, vsm);
  // fused dd + feature reductions (202 blocks x 512 threads)
  qf3_kernel<<<202, 512, 0, stream>>>(qh, ql, rh, rl, ph, rpe, fd);
  out_kernel<<<dim3((L + 1) / 2, BH), 256, 0, stream>>>(fd, v, vsm, qh);
  // output projection: 1-term, BK=128 (208 blocks)
  gemm128<0><<<dim3(16, 13), 256, 0, stream>>>(qh, Woh, bo, nullptr,
                                               (float*)d_out, nullptr, nullptr, nullptr);
}